// Round 10
// baseline (701.532 us; speedup 1.0000x reference)
//
#include <hip/hip_runtime.h>
#include <math.h>

#define NN 100000
#define NE 1600000
#define NG 512
#define NCLS 10
#define NEG 0.2f
#define BNEPS 1e-5f
#define BNB 1e-4f
#define MNEG -1e30f

#define NBUK 391      // buckets of 256 nodes
#define CHUNK2 6144   // edges per partition block
#define NB2 261       // ceil(NE/CHUNK2)
#define CAP3 5120     // per-bucket LDS capacity

typedef unsigned short u16;
typedef unsigned int u32;
typedef _Float16 f16;
typedef __attribute__((ext_vector_type(2))) f16 f16x2;
typedef __attribute__((ext_vector_type(8))) f16 f16x8;
typedef __attribute__((ext_vector_type(4))) float f32x4;

__device__ __forceinline__ float lrelu(float v) { return v > 0.f ? v : NEG * v; }
__device__ __forceinline__ u16 f2h(float x) { union { u16 s; f16 h; } c; c.h = (f16)x; return c.s; }
__device__ __forceinline__ float h2f(u16 s) { union { u16 s; f16 h; } c; c.s = s; return (float)c.h; }
__device__ __forceinline__ f16x2 u2h2(u32 u) { union { u32 u; f16x2 h; } c; c.u = u; return c.h; }
__device__ __forceinline__ u32 packp(float p) { u32 h = f2h(p); return h | (h << 16); }

// ---------------- BatchNorm stats (f32 input) ----------------
template<int C>
__global__ __launch_bounds__(256) void k_bn_part(const float* __restrict__ x, int rows,
                                                 float* __restrict__ part) {
    const int RPI = 256 / C;
    int col = threadIdx.x % C;
    int sub = threadIdx.x / C;
    int nb = gridDim.x;
    int rpb = (rows + nb - 1) / nb;
    int r0 = blockIdx.x * rpb;
    int r1 = min(rows, r0 + rpb);
    float s = 0.f, q = 0.f;
    for (int r = r0 + sub; r < r1; r += RPI) {
        float v = x[(size_t)r * C + col];
        s += v; q += v * v;
    }
    __shared__ float ls[256], lq[256];
    ls[threadIdx.x] = s; lq[threadIdx.x] = q;
    __syncthreads();
    for (int st = RPI / 2; st > 0; st >>= 1) {
        if (sub < st) {
            ls[threadIdx.x] += ls[threadIdx.x + st * C];
            lq[threadIdx.x] += lq[threadIdx.x + st * C];
        }
        __syncthreads();
    }
    if (sub == 0) {
        part[(size_t)blockIdx.x * C + col] = ls[col];
        part[(size_t)(nb + blockIdx.x) * C + col] = lq[col];
    }
}

// f16-input variant, C=64
__global__ __launch_bounds__(256) void k_bn_part16(const u16* __restrict__ x, int rows,
                                                   float* __restrict__ part) {
    int col = threadIdx.x & 63;
    int sub = threadIdx.x >> 6;
    int nb = gridDim.x;
    int rpb = (rows + nb - 1) / nb;
    int r0 = blockIdx.x * rpb;
    int r1 = min(rows, r0 + rpb);
    float s = 0.f, q = 0.f;
    for (int r = r0 + sub; r < r1; r += 4) {
        float v = h2f(x[(size_t)r * 64 + col]);
        s += v; q += v * v;
    }
    __shared__ float ls[256], lq[256];
    ls[threadIdx.x] = s; lq[threadIdx.x] = q;
    __syncthreads();
    for (int st = 2; st > 0; st >>= 1) {
        if (sub < st) {
            ls[threadIdx.x] += ls[threadIdx.x + st * 64];
            lq[threadIdx.x] += lq[threadIdx.x + st * 64];
        }
        __syncthreads();
    }
    if (sub == 0) {
        part[(size_t)blockIdx.x * 64 + col] = ls[col];
        part[(size_t)(nb + blockIdx.x) * 64 + col] = lq[col];
    }
}

// old small bn_adj (head path only)
__global__ __launch_bounds__(64) void k_bn_adj(const float* __restrict__ part, int nb, int rows, int C,
                                               const float* __restrict__ W, const float* __restrict__ b,
                                               int Ncol, float* __restrict__ sc, float* __restrict__ badj) {
    int c = threadIdx.x;
    __shared__ float shl[64];
    if (c < C) {
        float s = 0.f, q = 0.f;
        for (int bb = 0; bb < nb; bb++) {
            s += part[(size_t)bb * C + c];
            q += part[(size_t)(nb + bb) * C + c];
        }
        float mu = s / rows;
        float var = q / rows - mu * mu;
        float sl = rsqrtf(var + BNEPS);
        sc[c] = sl;
        shl[c] = BNB - mu * sl;
    }
    __syncthreads();
    if (c < Ncol) {
        float a = b ? b[c] : 0.f;
        for (int k = 0; k < C; k++) a += shl[k] * W[(size_t)k * Ncol + c];
        badj[c] = a;
    }
}

// fused: BN stats + badj + f16 MFMA B-fragments with sc folded into W
template<int C>
__global__ __launch_bounds__(256) void k_bnadjf(const float* __restrict__ part, int nb, int rows,
                                                const float* __restrict__ W, const float* __restrict__ b,
                                                float* __restrict__ badj, u16* __restrict__ Bff) {
    int t = threadIdx.x;
    int c = t & 63, seg = t >> 6;
    __shared__ float rs[4][64], rq[4][64];
    __shared__ float scl[64], shl[64];
    float s = 0.f, q = 0.f;
    if (c < C)
        for (int bb = seg; bb < nb; bb += 4) {
            s += part[(size_t)bb * C + c];
            q += part[(size_t)(nb + bb) * C + c];
        }
    rs[seg][c] = s; rq[seg][c] = q;
    __syncthreads();
    if (t < C) {
        float ss = rs[0][t] + rs[1][t] + rs[2][t] + rs[3][t];
        float qq = rq[0][t] + rq[1][t] + rq[2][t] + rq[3][t];
        float mu = ss / rows;
        float var = qq / rows - mu * mu;
        float sl = rsqrtf(var + BNEPS);
        scl[t] = sl; shl[t] = BNB - mu * sl;
    }
    __syncthreads();
    float a = 0.f;
    for (int k = seg; k < C; k += 4) a += shl[k] * W[(size_t)k * 64 + c];
    rs[seg][c] = a;
    __syncthreads();
    if (t < 64) badj[t] = (b ? b[t] : 0.f) + rs[0][t] + rs[1][t] + rs[2][t] + rs[3][t];
    const int KB = C / 32;
    for (int idx = t; idx < 4 * KB * 64 * 8; idx += 256) {
        int j = idx & 7;
        int lane = (idx >> 3) & 63;
        int kb = (idx >> 9) % KB;
        int ct = idx / (KB * 512);
        int k = kb * 32 + (lane >> 4) * 8 + j;
        int col = ct * 16 + (lane & 15);
        Bff[idx] = f2h(scl[k] * W[(size_t)k * 64 + col]);
    }
}

// ---------------- MFMA node GEMM ----------------
template<int KB, int EPI, bool F32IN>
__global__ __launch_bounds__(256) void k_gemm_mf(const void* __restrict__ xin,
                                                 const u16* __restrict__ Bff,
                                                 const float* __restrict__ badj,
                                                 u16* __restrict__ outb, int rows,
                                                 const float* __restrict__ att, float* __restrict__ hs,
                                                 const float* __restrict__ as_, const float* __restrict__ ad_,
                                                 float* __restrict__ asrc, float* __restrict__ adst) {
    int wid = threadIdx.x >> 6, lane = threadIdx.x & 63;
    int er = lane & 15, kh = lane >> 4;
    int r0 = blockIdx.x * 64;
    int rw = r0 + wid * 16;
    __shared__ u16 Dl[64][68];
    f16x8 bf[4][KB];
#pragma unroll
    for (int ct = 0; ct < 4; ct++)
#pragma unroll
        for (int kb = 0; kb < KB; kb++)
            bf[ct][kb] = *(const f16x8*)(Bff + ((size_t)(ct * KB + kb) * 64 + lane) * 8);
    f16x8 af[KB];
    int arow = rw + er;
    if (F32IN) {
        const float* xf = (const float*)xin;
        f16x8 av = (f16x8)(f16)0.f;
        if (arow < rows) {
            const float4* p = (const float4*)(xf + (size_t)arow * 32 + kh * 8);
            float4 v0 = p[0], v1 = p[1];
            av[0] = (f16)v0.x; av[1] = (f16)v0.y; av[2] = (f16)v0.z; av[3] = (f16)v0.w;
            av[4] = (f16)v1.x; av[5] = (f16)v1.y; av[6] = (f16)v1.z; av[7] = (f16)v1.w;
        }
        af[0] = av;
    } else {
        const u16* xh = (const u16*)xin;
#pragma unroll
        for (int kb = 0; kb < KB; kb++) {
            f16x8 av = (f16x8)(f16)0.f;
            if (arow < rows) av = *(const f16x8*)(xh + (size_t)arow * 64 + kb * 32 + kh * 8);
            af[kb] = av;
        }
    }
    f32x4 d[4];
#pragma unroll
    for (int ct = 0; ct < 4; ct++) {
        float bj = badj[ct * 16 + er];
        f32x4 cc = {bj, bj, bj, bj};
#pragma unroll
        for (int kb = 0; kb < KB; kb++)
            cc = __builtin_amdgcn_mfma_f32_16x16x32_f16(af[kb], bf[ct][kb], cc, 0, 0, 0);
        d[ct] = cc;
    }
#pragma unroll
    for (int ct = 0; ct < 4; ct++)
#pragma unroll
        for (int r = 0; r < 4; r++)
            Dl[wid * 16 + kh * 4 + r][ct * 16 + er] = f2h(d[ct][r]);
    if (EPI == 1) {
        float av[4];
#pragma unroll
        for (int ct = 0; ct < 4; ct++) av[ct] = att[ct * 16 + er];
#pragma unroll
        for (int r = 0; r < 4; r++) {
            float v = d[0][r] * av[0] + d[1][r] * av[1] + d[2][r] * av[2] + d[3][r] * av[3];
#pragma unroll
            for (int o = 1; o < 16; o <<= 1) v += __shfl_xor(v, o);
            int rr = rw + kh * 4 + r;
            if (er == 0 && rr < rows) hs[rr] = v;
        }
    }
    if (EPI == 2) {
        float a1v[4], a2v[4];
#pragma unroll
        for (int ct = 0; ct < 4; ct++) { a1v[ct] = as_[ct * 16 + er]; a2v[ct] = ad_[ct * 16 + er]; }
#pragma unroll
        for (int ct = 0; ct < 4; ct++) {
#pragma unroll
            for (int r = 0; r < 4; r++) {
                float s1 = d[ct][r] * a1v[ct], s2 = d[ct][r] * a2v[ct];
#pragma unroll
                for (int o = 1; o < 16; o <<= 1) { s1 += __shfl_xor(s1, o); s2 += __shfl_xor(s2, o); }
                int rr = rw + kh * 4 + r;
                if (er == 0 && rr < rows) {
                    asrc[(size_t)rr * 4 + ct] = s1;
                    adst[(size_t)rr * 4 + ct] = s2;
                }
            }
        }
    }
    __syncthreads();
    const u32* D32 = (const u32*)&Dl[0][0];
    u32* out32 = (u32*)outb;
    for (int idx = threadIdx.x; idx < 64 * 32; idx += 256) {
        int r = idx >> 5, c2 = idx & 31;
        int rr = r0 + r;
        if (rr < rows) out32[(size_t)rr * 32 + c2] = D32[r * 34 + c2];
    }
}

// ---------------- head GEMM (f32, small) ----------------
__global__ __launch_bounds__(256) void k_gemm_head(const float* __restrict__ x, const float* __restrict__ W,
                                                   const float* __restrict__ sc, const float* __restrict__ badj,
                                                   float* __restrict__ outf, int rows) {
    __shared__ float Ws[64 * 64];
    __shared__ float Xs[32 * 64];
    int r0 = blockIdx.x * 32;
    for (int i = threadIdx.x; i < 64 * 64; i += 256) Ws[i] = W[i];
    for (int i = threadIdx.x; i < 32 * 64; i += 256) {
        int r = i / 64, k = i % 64;
        int rr = r0 + r;
        Xs[i] = (rr < rows) ? x[(size_t)rr * 64 + k] * sc[k] : 0.f;
    }
    __syncthreads();
    int col = threadIdx.x & 63;
    int rg = threadIdx.x >> 6;
    float b0 = badj[col];
    float acc[8];
#pragma unroll
    for (int i = 0; i < 8; i++) acc[i] = b0;
    for (int k = 0; k < 64; k++) {
        float w = Ws[k * 64 + col];
#pragma unroll
        for (int i = 0; i < 8; i++) acc[i] += Xs[(rg * 8 + i) * 64 + k] * w;
    }
#pragma unroll
    for (int i = 0; i < 8; i++) {
        int r = r0 + rg * 8 + i;
        if (r < rows) outf[(size_t)r * 64 + col] = fmaxf(acc[i], 0.f);
    }
}

// folded attention weights + edgepre MFMA B-fragments
__global__ __launch_bounds__(768) void k_we(const float* __restrict__ cWe, const float* __restrict__ cae,
                                            const float* __restrict__ Wee, const float* __restrict__ att,
                                            const float* __restrict__ bee, float* __restrict__ wEbuf,
                                            u16* __restrict__ Bf1, u16* __restrict__ Bf2) {
    int t = threadIdx.x;
    int l = t >> 8;
    int h = (t >> 6) & 3;
    int k = t & 63;
    float a = 0.f;
    for (int d = 0; d < 16; d++)
        a += cWe[(size_t)l * 4096 + k * 64 + h * 16 + d] * cae[l * 64 + h * 16 + d];
    wEbuf[t] = a;
    if (t < 16) {
        float v = 0.f;
        for (int j = 0; j < 64; j++) v += Wee[t * 64 + j] * att[j];
        wEbuf[768 + t] = v;
    }
    if (t == 16) {
        float v = 0.f;
        for (int j = 0; j < 64; j++) v += bee[j] * att[j];
        wEbuf[784] = v;
    }
    for (int idx = t; idx < 4 * 64 * 8; idx += 768) {
        int cb = idx >> 9, ln = (idx >> 3) & 63, j = idx & 7;
        int col = cb * 16 + (ln & 15);
        int kk = (ln >> 4) * 8 + j;
        float v = (kk < 16) ? Wee[kk * 64 + col] : 0.f;
        Bf1[idx] = f2h(v);
    }
    __syncthreads();
    for (int idx = t; idx < 2 * 64 * 8; idx += 768) {
        int kb = idx >> 9, ln = (idx >> 3) & 63, j = idx & 7;
        int n = ln & 15;
        int kk = kb * 32 + (ln >> 4) * 8 + j;
        float v = (n < 12) ? wEbuf[n * 64 + kk] : 0.f;
        Bf2[idx] = f2h(v);
    }
}

// ---------------- CSR build via LDS counting sort ----------------
__global__ __launch_bounds__(256) void k_bhist(const int* __restrict__ dst, int* __restrict__ hist) {
    __shared__ int lh[512];
    int t = threadIdx.x;
    lh[t] = 0; lh[t + 256] = 0;
    __syncthreads();
    int base = blockIdx.x * CHUNK2;
    int cnt = min(CHUNK2, NE - base);
    for (int i = t; i < cnt; i += 256) atomicAdd(&lh[dst[base + i] >> 8], 1);
    __syncthreads();
    for (int b = t; b < NBUK; b += 256) hist[blockIdx.x * NBUK + b] = lh[b];
}

__global__ __launch_bounds__(256) void k_colsum(const int* __restrict__ hist, int* __restrict__ colsum) {
    int col = blockIdx.x;
    int t = threadIdx.x;
    int s = 0;
    for (int b = t; b < NB2; b += 256) s += hist[b * NBUK + col];
    __shared__ int ls[256];
    ls[t] = s;
    __syncthreads();
    for (int st = 128; st; st >>= 1) {
        if (t < st) ls[t] += ls[t + st];
        __syncthreads();
    }
    if (t == 0) colsum[col] = ls[0];
}

__global__ __launch_bounds__(512) void k_bukscan(const int* __restrict__ colsum,
                                                 int* __restrict__ bucketBase, int* __restrict__ rowp) {
    __shared__ int ls[512];
    int t = threadIdx.x;
    int v = (t < NBUK) ? colsum[t] : 0;
    ls[t] = v;
    __syncthreads();
    for (int off = 1; off < 512; off <<= 1) {
        int a = (t >= off) ? ls[t - off] : 0;
        __syncthreads();
        ls[t] += a;
        __syncthreads();
    }
    if (t < NBUK) bucketBase[t] = ls[t] - v;
    if (t == 0) { bucketBase[NBUK] = NE; rowp[NN] = NE; }
}

__global__ __launch_bounds__(512) void k_coloffs(const int* __restrict__ hist,
                                                 const int* __restrict__ bucketBase, int* __restrict__ offs) {
    int col = blockIdx.x;
    int t = threadIdx.x;
    __shared__ int ls[512];
    int v = (t < NB2) ? hist[(size_t)t * NBUK + col] : 0;
    ls[t] = v;
    __syncthreads();
    for (int off = 1; off < 512; off <<= 1) {
        int a = (t >= off) ? ls[t - off] : 0;
        __syncthreads();
        ls[t] += a;
        __syncthreads();
    }
    if (t < NB2) offs[(size_t)t * NBUK + col] = bucketBase[col] + ls[t] - v;
}

__global__ __launch_bounds__(256) void k_part(const int* __restrict__ src, const int* __restrict__ dst,
                                              const int* __restrict__ offs, int2* __restrict__ seTmp) {
    __shared__ int lhist[512];
    __shared__ int lstart[NBUK + 1];
    __shared__ int lcur[NBUK];
    __shared__ int loffs[NBUK];
    __shared__ int2 stage[CHUNK2];
    int t = threadIdx.x;
    int base = blockIdx.x * CHUNK2;
    int cnt = min(CHUNK2, NE - base);
    int blkrow = blockIdx.x * NBUK;
    lhist[t] = 0; lhist[t + 256] = 0;
    __syncthreads();
    for (int i = t; i < cnt; i += 256) atomicAdd(&lhist[dst[base + i] >> 8], 1);
    __syncthreads();
    for (int off = 1; off < 512; off <<= 1) {
        int v0 = (t >= off) ? lhist[t - off] : 0;
        int v1 = lhist[t + 256 - off];
        __syncthreads();
        lhist[t] += v0; lhist[t + 256] += v1;
        __syncthreads();
    }
    if (t == 0) lstart[0] = 0;
    lstart[t + 1] = lhist[t];
    if (t + 257 <= NBUK) lstart[t + 257] = lhist[t + 256];
    __syncthreads();
    for (int b = t; b < NBUK; b += 256) {
        lcur[b] = lstart[b];
        loffs[b] = offs[blkrow + b];
    }
    __syncthreads();
    for (int i = t; i < cnt; i += 256) {
        int e = base + i;
        int d = dst[e];
        int b = d >> 8;
        int pos = atomicAdd(&lcur[b], 1);
        int2 v; v.x = src[e] | (b << 17); v.y = e | ((d & 255) << 21);
        stage[pos] = v;
    }
    __syncthreads();
    for (int q = t; q < cnt; q += 256) {
        int2 v = stage[q];
        int b = ((u32)v.x) >> 17;
        int2 o; o.x = v.x & 0x1FFFF; o.y = v.y;
        seTmp[loffs[b] + (q - lstart[b])] = o;
    }
}

__global__ __launch_bounds__(256) void k_bucket(const int2* __restrict__ seTmp,
                                                const int* __restrict__ bucketBase,
                                                int2* __restrict__ se, int* __restrict__ rowp) {
    int b = blockIdx.x;
    int t = threadIdx.x;
    int beg = bucketBase[b], end = bucketBase[b + 1];
    int cnt = end - beg;
    __shared__ int lhist[256], lscan[256], lcur[256];
    __shared__ int2 ebuf[CAP3];
    lhist[t] = 0;
    __syncthreads();
    for (int i = t; i < cnt; i += 256)
        atomicAdd(&lhist[((u32)seTmp[beg + i].y) >> 21], 1);
    __syncthreads();
    lscan[t] = lhist[t];
    __syncthreads();
    for (int off = 1; off < 256; off <<= 1) {
        int v = (t >= off) ? lscan[t - off] : 0;
        __syncthreads();
        lscan[t] += v;
        __syncthreads();
    }
    int excl = lscan[t] - lhist[t];
    lcur[t] = excl;
    int node = b * 256 + t;
    if (node < NN) rowp[node] = beg + excl;
    __syncthreads();
    if (cnt <= CAP3) {
        for (int i = t; i < cnt; i += 256) {
            int2 v = seTmp[beg + i];
            int dl = ((u32)v.y) >> 21;
            int pos = atomicAdd(&lcur[dl], 1);
            int2 o; o.x = v.x; o.y = v.y & 0x1FFFFF;
            ebuf[pos] = o;
        }
        __syncthreads();
        for (int q = t; q < cnt; q += 256) se[beg + q] = ebuf[q];
    } else {
        for (int i = t; i < cnt; i += 256) {
            int2 v = seTmp[beg + i];
            int dl = ((u32)v.y) >> 21;
            int pos = atomicAdd(&lcur[dl], 1);
            int2 o; o.x = v.x; o.y = v.y & 0x1FFFFF;
            se[beg + pos] = o;
        }
    }
}

// ---------------- edge precompute via MFMA: 32 edges/wave ----------------
__global__ __launch_bounds__(256) void k_edgepre(const float* __restrict__ ea,
                                                 const u16* __restrict__ Bf1, const u16* __restrict__ Bf2,
                                                 const float* __restrict__ bee, const float* __restrict__ wEbuf,
                                                 const int2* __restrict__ se,
                                                 float* __restrict__ heatt, ushort4* __restrict__ aedH) {
    int wid = threadIdx.x >> 6, lane = threadIdx.x & 63;
    int p0 = (blockIdx.x * 4 + wid) * 32;
    __shared__ f16 EaD[4][32][24];
    __shared__ f16 Pl[4][32][72];
    f16x8 bf1[4], bf2[2];
#pragma unroll
    for (int cb = 0; cb < 4; cb++) bf1[cb] = *(const f16x8*)(Bf1 + ((size_t)cb * 64 + lane) * 8);
#pragma unroll
    for (int kb = 0; kb < 2; kb++) bf2[kb] = *(const f16x8*)(Bf2 + ((size_t)kb * 64 + lane) * 8);
    int e = lane & 31, q = lane >> 5;
    int ei = se[p0 + e].y;
    const float4* pa = (const float4*)(ea + (size_t)ei * 16 + q * 8);
    float4 v0 = pa[0], v1 = pa[1];
    {
        const float* va = wEbuf + 768 + q * 8;
        float part = v0.x * va[0] + v0.y * va[1] + v0.z * va[2] + v0.w * va[3]
                   + v1.x * va[4] + v1.y * va[5] + v1.z * va[6] + v1.w * va[7];
        float po = __shfl_xor(part, 32);
        if (lane < 32) heatt[p0 + e] = part + po + wEbuf[784];
    }
    {
        f16x8 t;
        t[0] = (f16)v0.x; t[1] = (f16)v0.y; t[2] = (f16)v0.z; t[3] = (f16)v0.w;
        t[4] = (f16)v1.x; t[5] = (f16)v1.y; t[6] = (f16)v1.z; t[7] = (f16)v1.w;
        *(f16x8*)&EaD[wid][e][q * 8] = t;
    }
    __builtin_amdgcn_wave_barrier();
    int er = lane & 15, kh = lane >> 4;
    f16x8 a0f = (f16x8)(f16)0.f, a1f = (f16x8)(f16)0.f;
    if (kh < 2) {
        a0f = *(const f16x8*)&EaD[wid][er][kh * 8];
        a1f = *(const f16x8*)&EaD[wid][16 + er][kh * 8];
    }
    f32x4 z = {0.f, 0.f, 0.f, 0.f};
    f32x4 d0[4], d1[4];
#pragma unroll
    for (int ct = 0; ct < 4; ct++) {
        d0[ct] = __builtin_amdgcn_mfma_f32_16x16x32_f16(a0f, bf1[ct], z, 0, 0, 0);
        d1[ct] = __builtin_amdgcn_mfma_f32_16x16x32_f16(a1f, bf1[ct], z, 0, 0, 0);
    }
    {
#pragma unroll
        for (int ct = 0; ct < 4; ct++) {
            float bb = bee[ct * 16 + er];
#pragma unroll
            for (int r = 0; r < 4; r++) {
                Pl[wid][kh * 4 + r][ct * 16 + er] = (f16)fmaxf(d0[ct][r] + bb, 0.f);
                Pl[wid][16 + kh * 4 + r][ct * 16 + er] = (f16)fmaxf(d1[ct][r] + bb, 0.f);
            }
        }
    }
    __builtin_amdgcn_wave_barrier();
    f16x8 pa00 = *(const f16x8*)&Pl[wid][er][kh * 8];
    f16x8 pa01 = *(const f16x8*)&Pl[wid][er][32 + kh * 8];
    f16x8 pa10 = *(const f16x8*)&Pl[wid][16 + er][kh * 8];
    f16x8 pa11 = *(const f16x8*)&Pl[wid][16 + er][32 + kh * 8];
    f32x4 dd0 = __builtin_amdgcn_mfma_f32_16x16x32_f16(pa00, bf2[0], z, 0, 0, 0);
    dd0 = __builtin_amdgcn_mfma_f32_16x16x32_f16(pa01, bf2[1], dd0, 0, 0, 0);
    f32x4 dd1 = __builtin_amdgcn_mfma_f32_16x16x32_f16(pa10, bf2[0], z, 0, 0, 0);
    dd1 = __builtin_amdgcn_mfma_f32_16x16x32_f16(pa11, bf2[1], dd1, 0, 0, 0);
    __builtin_amdgcn_wave_barrier();
#pragma unroll
    for (int r = 0; r < 4; r++) {
        EaD[wid][kh * 4 + r][er] = (f16)dd0[r];
        EaD[wid][16 + kh * 4 + r][er] = (f16)dd1[r];
    }
    __builtin_amdgcn_wave_barrier();
    {
        int e2 = lane & 31, l3 = lane >> 5;
        ushort4 o = *(const ushort4*)&EaD[wid][e2][l3 * 4];
        aedH[(size_t)l3 * NE + p0 + e2] = o;
        if (lane < 32) {
            ushort4 o2 = *(const ushort4*)&EaD[wid][lane][8];
            aedH[(size_t)2 * NE + p0 + lane] = o2;
        }
    }
}

// ---------------- EGAT aggregation: 4 cols/lane, packed f16 pk_fma gather ----------------
__global__ __launch_bounds__(256) void k_egat_agg(const int* __restrict__ rowp, const int2* __restrict__ se,
                                                  const float* __restrict__ heatt, const float* __restrict__ hs,
                                                  const u16* __restrict__ hb, u16* __restrict__ xout) {
    int wid = threadIdx.x >> 6, lane = threadIdx.x & 63;
    int n = blockIdx.x * 4 + wid;
    if (n >= NN) return;
    int beg = rowp[n], deg = rowp[n + 1] - beg;
    if (deg == 0) { xout[(size_t)n * 64 + lane] = 0; return; }
    float hsn = hs[n];
    __shared__ u32 plp[4][64];
    __shared__ int soff[4][64];
    if (deg <= 64) {
        int s = 0; float lg = MNEG;
        if (lane < deg) {
            int2 pr = se[beg + lane];
            s = pr.x;
            lg = lrelu(hs[s] + hsn + heatt[beg + lane]);
        }
        float m = lg;
#pragma unroll
        for (int o = 32; o; o >>= 1) m = fmaxf(m, __shfl_xor(m, o));
        float e = (lane < deg) ? __expf(lg - m) : 0.f;
        float sm = e;
#pragma unroll
        for (int o = 32; o; o >>= 1) sm += __shfl_xor(sm, o);
        float p = e * (1.f / sm);
        plp[wid][lane] = packp(p);
        soff[wid][lane] = s << 7;   // s * 128 bytes
        __builtin_amdgcn_wave_barrier();
        int cq = lane & 15, q = lane >> 4;
        const u32* prow = &plp[wid][0];
        const int* srow = &soff[wid][0];
        const char* hp = (const char*)hb + cq * 8;
        f16x2 a01a = (f16x2)(f16)0.f, a23a = (f16x2)(f16)0.f;
        f16x2 a01b = (f16x2)(f16)0.f, a23b = (f16x2)(f16)0.f;
        for (int j = 0; j < deg; j += 8) {
            int e0 = j + q, e1 = j + 4 + q;
            u32 pp0 = prow[e0]; int o0 = srow[e0];
            u32 pp1 = prow[e1]; int o1 = srow[e1];
            uint2 w0 = *(const uint2*)(hp + o0);
            uint2 w1 = *(const uint2*)(hp + o1);
            f16x2 q0 = u2h2(pp0), q1 = u2h2(pp1);
            a01a = q0 * u2h2(w0.x) + a01a;
            a23a = q0 * u2h2(w0.y) + a23a;
            a01b = q1 * u2h2(w1.x) + a01b;
            a23b = q1 * u2h2(w1.y) + a23b;
        }
        float c0 = (float)a01a[0] + (float)a01b[0];
        float c1 = (float)a01a[1] + (float)a01b[1];
        float c2 = (float)a23a[0] + (float)a23b[0];
        float c3 = (float)a23a[1] + (float)a23b[1];
        c0 += __shfl_xor(c0, 16); c0 += __shfl_xor(c0, 32);
        c1 += __shfl_xor(c1, 16); c1 += __shfl_xor(c1, 32);
        c2 += __shfl_xor(c2, 16); c2 += __shfl_xor(c2, 32);
        c3 += __shfl_xor(c3, 16); c3 += __shfl_xor(c3, 32);
        if (lane < 16) {
            ushort4 o;
            o.x = f2h(fmaxf(c0, 0.f));
            o.y = f2h(fmaxf(c1, 0.f));
            o.z = f2h(fmaxf(c2, 0.f));
            o.w = f2h(fmaxf(c3, 0.f));
            *(ushort4*)(xout + (size_t)n * 64 + cq * 4) = o;
        }
    } else {
        float m = MNEG, sm = 0.f;
        for (int i = lane; i < deg; i += 64) {
            int2 pr = se[beg + i];
            float v = lrelu(hs[pr.x] + hsn + heatt[beg + i]);
            float mn = fmaxf(m, v);
            sm = sm * __expf(m - mn) + __expf(v - mn);
            m = mn;
        }
#pragma unroll
        for (int o = 32; o; o >>= 1) {
            float mo = __shfl_xor(m, o), so = __shfl_xor(sm, o);
            float mn = fmaxf(m, mo);
            sm = sm * __expf(m - mn) + so * __expf(mo - mn);
            m = mn;
        }
        float inv = 1.f / sm;
        float acc0 = 0.f;
        for (int base = 0; base < deg; base += 64) {
            int i = base + lane;
            int s = 0; float p = 0.f;
            if (i < deg) {
                int2 pr = se[beg + i];
                s = pr.x;
                p = __expf(lrelu(hs[s] + hsn + heatt[beg + i]) - m) * inv;
            }
            int mm = min(64, deg - base);
            for (int j = 0; j < mm; j++) {
                int s0 = __shfl(s, j); float q0 = __shfl(p, j);
                acc0 = fmaf(q0, h2f(hb[(size_t)s0 * 64 + lane]), acc0);
            }
        }
        xout[(size_t)n * 64 + lane] = f2h(fmaxf(acc0, 0.f));
    }
}

// ---------------- conv aggregation: 4 cols/lane, packed f16 pk_fma gather ----------------
__global__ __launch_bounds__(256) void k_conv_agg(const int* __restrict__ rowp, const int2* __restrict__ se,
                                                  const ushort4* __restrict__ aedH, const float* __restrict__ asrc,
                                                  const float* __restrict__ adst, const u16* __restrict__ hb,
                                                  const float* __restrict__ bias, u16* __restrict__ xout) {
    int wid = threadIdx.x >> 6, lane = threadIdx.x & 63;
    int n = blockIdx.x * 4 + wid;
    if (n >= NN) return;
    int beg = rowp[n], deg = rowp[n + 1] - beg;
    if (deg == 0) { xout[(size_t)n * 64 + lane] = f2h(fmaxf(bias[lane], 0.f)); return; }
    float4 an = ((const float4*)adst)[n];
    __shared__ u32 plp[4][4][64];
    __shared__ int soff[4][64];
    __shared__ float plsF[4][4][72];
    __shared__ int slF[4][64];
    if (deg <= 64) {
        int s = 0;
        float l0 = MNEG, l1 = MNEG, l2 = MNEG, l3 = MNEG;
        if (lane < deg) {
            s = se[beg + lane].x;
            float4 as4 = ((const float4*)asrc)[s];
            ushort4 u = aedH[beg + lane];
            l0 = lrelu(as4.x + an.x + h2f(u.x));
            l1 = lrelu(as4.y + an.y + h2f(u.y));
            l2 = lrelu(as4.z + an.z + h2f(u.z));
            l3 = lrelu(as4.w + an.w + h2f(u.w));
        }
        float m0 = l0, m1 = l1, m2 = l2, m3 = l3;
#pragma unroll
        for (int o = 32; o; o >>= 1) {
            m0 = fmaxf(m0, __shfl_xor(m0, o)); m1 = fmaxf(m1, __shfl_xor(m1, o));
            m2 = fmaxf(m2, __shfl_xor(m2, o)); m3 = fmaxf(m3, __shfl_xor(m3, o));
        }
        float e0 = (lane < deg) ? __expf(l0 - m0) : 0.f;
        float e1 = (lane < deg) ? __expf(l1 - m1) : 0.f;
        float e2 = (lane < deg) ? __expf(l2 - m2) : 0.f;
        float e3 = (lane < deg) ? __expf(l3 - m3) : 0.f;
        float s0 = e0, s1 = e1, s2 = e2, s3 = e3;
#pragma unroll
        for (int o = 32; o; o >>= 1) {
            s0 += __shfl_xor(s0, o); s1 += __shfl_xor(s1, o);
            s2 += __shfl_xor(s2, o); s3 += __shfl_xor(s3, o);
        }
        plp[wid][0][lane] = packp(e0 * (1.f / s0));
        plp[wid][1][lane] = packp(e1 * (1.f / s1));
        plp[wid][2][lane] = packp(e2 * (1.f / s2));
        plp[wid][3][lane] = packp(e3 * (1.f / s3));
        soff[wid][lane] = s << 7;
        __builtin_amdgcn_wave_barrier();
        int cq = lane & 15, q = lane >> 4;
        const u32* prow = &plp[wid][cq >> 2][0];
        const int* srow = &soff[wid][0];
        const char* hp = (const char*)hb + cq * 8;
        f16x2 a01a = (f16x2)(f16)0.f, a23a = (f16x2)(f16)0.f;
        f16x2 a01b = (f16x2)(f16)0.f, a23b = (f16x2)(f16)0.f;
        for (int j = 0; j < deg; j += 8) {
            int e0i = j + q, e1i = j + 4 + q;
            u32 pp0 = prow[e0i]; int o0 = srow[e0i];
            u32 pp1 = prow[e1i]; int o1 = srow[e1i];
            uint2 w0 = *(const uint2*)(hp + o0);
            uint2 w1 = *(const uint2*)(hp + o1);
            f16x2 q0 = u2h2(pp0), q1 = u2h2(pp1);
            a01a = q0 * u2h2(w0.x) + a01a;
            a23a = q0 * u2h2(w0.y) + a23a;
            a01b = q1 * u2h2(w1.x) + a01b;
            a23b = q1 * u2h2(w1.y) + a23b;
        }
        float c0 = (float)a01a[0] + (float)a01b[0];
        float c1 = (float)a01a[1] + (float)a01b[1];
        float c2 = (float)a23a[0] + (float)a23b[0];
        float c3 = (float)a23a[1] + (float)a23b[1];
        c0 += __shfl_xor(c0, 16); c0 += __shfl_xor(c0, 32);
        c1 += __shfl_xor(c1, 16); c1 += __shfl_xor(c1, 32);
        c2 += __shfl_xor(c2, 16); c2 += __shfl_xor(c2, 32);
        c3 += __shfl_xor(c3, 16); c3 += __shfl_xor(c3, 32);
        if (lane < 16) {
            ushort4 o;
            o.x = f2h(fmaxf(c0 + bias[cq * 4 + 0], 0.f));
            o.y = f2h(fmaxf(c1 + bias[cq * 4 + 1], 0.f));
            o.z = f2h(fmaxf(c2 + bias[cq * 4 + 2], 0.f));
            o.w = f2h(fmaxf(c3 + bias[cq * 4 + 3], 0.f));
            *(ushort4*)(xout + (size_t)n * 64 + cq * 4) = o;
        }
    } else {
        int hq = lane >> 4;
        float m0 = MNEG, m1 = MNEG, m2 = MNEG, m3 = MNEG;
        float s0 = 0.f, s1 = 0.f, s2 = 0.f, s3 = 0.f;
        for (int i = lane; i < deg; i += 64) {
            int s = se[beg + i].x;
            float4 as4 = ((const float4*)asrc)[s];
            ushort4 u = aedH[beg + i];
            float l0 = lrelu(as4.x + an.x + h2f(u.x));
            float l1 = lrelu(as4.y + an.y + h2f(u.y));
            float l2 = lrelu(as4.z + an.z + h2f(u.z));
            float l3 = lrelu(as4.w + an.w + h2f(u.w));
            float n0 = fmaxf(m0, l0); s0 = s0 * __expf(m0 - n0) + __expf(l0 - n0); m0 = n0;
            float n1 = fmaxf(m1, l1); s1 = s1 * __expf(m1 - n1) + __expf(l1 - n1); m1 = n1;
            float n2 = fmaxf(m2, l2); s2 = s2 * __expf(m2 - n2) + __expf(l2 - n2); m2 = n2;
            float n3 = fmaxf(m3, l3); s3 = s3 * __expf(m3 - n3) + __expf(l3 - n3); m3 = n3;
        }
#pragma unroll
        for (int o = 32; o; o >>= 1) {
            float mo, so, mn;
            mo = __shfl_xor(m0, o); so = __shfl_xor(s0, o); mn = fmaxf(m0, mo);
            s0 = s0 * __expf(m0 - mn) + so * __expf(mo - mn); m0 = mn;
            mo = __shfl_xor(m1, o); so = __shfl_xor(s1, o); mn = fmaxf(m1, mo);
            s1 = s1 * __expf(m1 - mn) + so * __expf(mo - mn); m1 = mn;
            mo = __shfl_xor(m2, o); so = __shfl_xor(s2, o); mn = fmaxf(m2, mo);
            s2 = s2 * __expf(m2 - mn) + so * __expf(mo - mn); m2 = mn;
            mo = __shfl_xor(m3, o); so = __shfl_xor(s3, o); mn = fmaxf(m3, mo);
            s3 = s3 * __expf(m3 - mn) + so * __expf(mo - mn); m3 = mn;
        }
        float i0 = 1.f / s0, i1 = 1.f / s1, i2 = 1.f / s2, i3 = 1.f / s3;
        float acc0 = 0.f;
        for (int base = 0; base < deg; base += 64) {
            int i = base + lane;
            if (i < deg) {
                int s = se[beg + i].x;
                float4 as4 = ((const float4*)asrc)[s];
                ushort4 u = aedH[beg + i];
                plsF[wid][0][lane] = __expf(lrelu(as4.x + an.x + h2f(u.x)) - m0) * i0;
                plsF[wid][1][lane] = __expf(lrelu(as4.y + an.y + h2f(u.y)) - m1) * i1;
                plsF[wid][2][lane] = __expf(lrelu(as4.z + an.z + h2f(u.z)) - m2) * i2;
                plsF[wid][3][lane] = __expf(lrelu(as4.w + an.w + h2f(u.w)) - m3) * i3;
                slF[wid][lane] = s;
            }
            __builtin_amdgcn_wave_barrier();
            int mm = min(64, deg - base);
            const float* prow = &plsF[wid][hq][0];
            const int* srow = &slF[wid][0];
            for (int j = 0; j < mm; j++)
                acc0 = fmaf(prow[j], h2f(hb[(size_t)srow[j] * 64 + lane]), acc0);
            __builtin_amdgcn_wave_barrier();
        }
        xout[(size_t)n * 64 + lane] = f2h(fmaxf(acc0 + bias[lane], 0.f));
    }
}

// ---------------- pool + head ----------------
__device__ __forceinline__ int lowerb(const int* a, int n, int key) {
    int lo = 0, hi = n;
    while (lo < hi) {
        int mid = (lo + hi) >> 1;
        if (a[mid] < key) lo = mid + 1; else hi = mid;
    }
    return lo;
}

__global__ __launch_bounds__(256) void k_pool(const u16* __restrict__ x, const int* __restrict__ batch,
                                              float* __restrict__ g) {
    int gr = blockIdx.x;
    int lane = threadIdx.x & 63;
    int sub = threadIdx.x >> 6;
    int beg = lowerb(batch, NN, gr);
    int end = lowerb(batch, NN, gr + 1);
    float acc = 0.f;
    for (int i = beg + sub; i < end; i += 4) acc += h2f(x[(size_t)i * 64 + lane]);
    __shared__ float ls[4][64];
    ls[sub][lane] = acc;
    __syncthreads();
    if (sub == 0)
        g[(size_t)gr * 64 + lane] = ls[0][lane] + ls[1][lane] + ls[2][lane] + ls[3][lane];
}

__global__ __launch_bounds__(64) void k_cls(const float* __restrict__ y, const float* __restrict__ W,
                                            const float* __restrict__ sc, const float* __restrict__ badj,
                                            float* __restrict__ out) {
    int r = blockIdx.x, lane = threadIdx.x;
    __shared__ float yr[64];
    yr[lane] = y[(size_t)r * 64 + lane] * sc[lane];
    __syncthreads();
    float lg = -INFINITY;
    if (lane < NCLS) {
        float a = badj[lane];
        for (int k = 0; k < 64; k++) a += yr[k] * W[k * NCLS + lane];
        lg = a;
    }
    float mx = lg;
#pragma unroll
    for (int o = 32; o; o >>= 1) mx = fmaxf(mx, __shfl_xor(mx, o));
    float e = (lane < NCLS) ? expf(lg - mx) : 0.f;
    float s = e;
#pragma unroll
    for (int o = 32; o; o >>= 1) s += __shfl_xor(s, o);
    if (lane < NCLS) out[(size_t)r * NCLS + lane] = lg - mx - logf(s);
}

extern "C" void kernel_launch(void* const* d_in, const int* in_sizes, int n_in,
                              void* d_out, int out_size, void* d_ws, size_t ws_size,
                              hipStream_t stream) {
    const float* x0  = (const float*)d_in[0];
    const float* ea  = (const float*)d_in[1];
    const int* eidx  = (const int*)d_in[2];
    const int* batch = (const int*)d_in[3];
    const float* Wx  = (const float*)d_in[4];
    const float* bx  = (const float*)d_in[5];
    const float* Wee = (const float*)d_in[6];
    const float* bee = (const float*)d_in[7];
    const float* att = (const float*)d_in[8];
    const float* cW  = (const float*)d_in[9];
    const float* cWe = (const float*)d_in[10];
    const float* cas = (const float*)d_in[11];
    const float* cad = (const float*)d_in[12];
    const float* cae = (const float*)d_in[13];
    const float* cb  = (const float*)d_in[14];
    const float* lW  = (const float*)d_in[15];
    const float* lb  = (const float*)d_in[16];
    const float* clW = (const float*)d_in[17];
    const float* clb = (const float*)d_in[18];
    float* out = (float*)d_out;

    const int* srcA = eidx;
    const int* dstA = eidx + NE;

    char* w = (char*)d_ws;
    size_t off = 0;
    auto alloc = [&](size_t bytes) -> void* {
        void* p = w + off;
        off += (bytes + 255) & ~(size_t)255;
        return p;
    };
    u16* hbA      = (u16*)alloc((size_t)NN * 64 * 2);
    u16* B16      = (u16*)alloc((size_t)NN * 64 * 2);
    float* hs     = (float*)alloc((size_t)NN * 4);
    float* asrc   = (float*)alloc((size_t)NN * 4 * 4);
    float* adst   = (float*)alloc((size_t)NN * 4 * 4);
    float* heatt  = (float*)alloc((size_t)NE * 4);
    ushort4* aedH = (ushort4*)alloc((size_t)3 * NE * 8);
    int2* se      = (int2*)alloc((size_t)NE * 8);
    int* rowp     = (int*)alloc((size_t)(NN + 1) * 4);
    int* hist     = (int*)alloc((size_t)NB2 * NBUK * 4);
    int* offs     = (int*)alloc((size_t)NB2 * NBUK * 4);
    int* bucketBase = (int*)alloc((size_t)(NBUK + 1) * 4);
    int* colsum   = (int*)alloc((size_t)NBUK * 4);
    float* part   = (float*)alloc((size_t)2 * 200 * 64 * 4);
    float* badj   = (float*)alloc(64 * 4);
    float* wEbuf  = (float*)alloc(800 * 4);
    u16* Bf1      = (u16*)alloc(4 * 64 * 8 * 2);
    u16* Bf2      = (u16*)alloc(2 * 64 * 8 * 2);
    u16* Bff      = (u16*)alloc(8 * 64 * 8 * 2);
    float* g      = (float*)alloc((size_t)NG * 64 * 4);
    float* y      = (float*)alloc((size_t)NG * 64 * 4);
    float* badj2  = (float*)alloc(64 * 4);
    float* badj3  = (float*)alloc(64 * 4);
    float* sc2    = (float*)alloc(64 * 4);
    float* sc3    = (float*)alloc(64 * 4);
    if (off > ws_size) return;

    int2* seTmp = (int2*)aedH;

    const int NB = 200;
    const int GEMMB = (NN + 63) / 64;

    // ---- CSR build ----
    k_bhist<<<NB2, 256, 0, stream>>>(dstA, hist);
    k_colsum<<<NBUK, 256, 0, stream>>>(hist, colsum);
    k_bukscan<<<1, 512, 0, stream>>>(colsum, bucketBase, rowp);
    k_coloffs<<<NBUK, 512, 0, stream>>>(hist, bucketBase, offs);
    k_part<<<NB2, 256, 0, stream>>>(srcA, dstA, offs, seTmp);
    k_bucket<<<NBUK, 256, 0, stream>>>(seTmp, bucketBase, se, rowp);

    // ---- folded attention weights ----
    k_we<<<1, 768, 0, stream>>>(cWe, cae, Wee, att, bee, wEbuf, Bf1, Bf2);

    // ---- BN(x0) + EGAT node GEMM ----
    k_bn_part<32><<<NB, 256, 0, stream>>>(x0, NN, part);
    k_bnadjf<32><<<1, 256, 0, stream>>>(part, NB, NN, Wx, bx, badj, Bff);
    k_gemm_mf<1, 1, true><<<GEMMB, 256, 0, stream>>>(
        x0, Bff, badj, hbA, NN, att, hs, nullptr, nullptr, nullptr, nullptr);

    // ---- edge precompute ----
    k_edgepre<<<NE / 128, 256, 0, stream>>>(ea, Bf1, Bf2, bee, wEbuf, se, heatt, aedH);

    // ---- EGAT aggregation ----
    k_egat_agg<<<(NN + 3) / 4, 256, 0, stream>>>(rowp, se, heatt, hs, hbA, B16);

    // ---- 3 GATConv layers ----
    for (int l = 0; l < 3; l++) {
        k_bn_part16<<<NB, 256, 0, stream>>>(B16, NN, part);
        k_bnadjf<64><<<1, 256, 0, stream>>>(part, NB, NN, cW + (size_t)l * 4096, nullptr, badj, Bff);
        k_gemm_mf<2, 2, false><<<GEMMB, 256, 0, stream>>>(
            B16, Bff, badj, hbA, NN, nullptr, nullptr,
            cas + l * 64, cad + l * 64, asrc, adst);
        k_conv_agg<<<(NN + 3) / 4, 256, 0, stream>>>(rowp, se, aedH + (size_t)l * NE, asrc, adst, hbA,
                                                     cb + l * 64, B16);
    }

    // ---- pool + head ----
    k_pool<<<NG, 256, 0, stream>>>(B16, batch, g);

    k_bn_part<64><<<2, 256, 0, stream>>>(g, NG, part);
    k_bn_adj<<<1, 64, 0, stream>>>(part, 2, NG, 64, lW, lb, 64, sc2, badj2);
    k_gemm_head<<<(NG + 31) / 32, 256, 0, stream>>>(g, lW, sc2, badj2, y, NG);

    k_bn_part<64><<<2, 256, 0, stream>>>(y, NG, part);
    k_bn_adj<<<1, 64, 0, stream>>>(part, 2, NG, 64, clW, clb, 10, sc3, badj3);
    k_cls<<<NG, 64, 0, stream>>>(y, clW, sc3, badj3, out);
}

// Round 11
// 689.105 us; speedup vs baseline: 1.0180x; 1.0180x over previous
//
#include <hip/hip_runtime.h>
#include <math.h>

#define NN 100000
#define NE 1600000
#define NG 512
#define NCLS 10
#define NEG 0.2f
#define BNEPS 1e-5f
#define BNB 1e-4f
#define MNEG -1e30f

#define NBUK 391      // buckets of 256 nodes
#define CHUNK2 6144   // edges per partition block
#define NB2 261       // ceil(NE/CHUNK2)
#define CAP3 5120     // per-bucket LDS capacity

typedef unsigned short u16;
typedef unsigned int u32;
typedef _Float16 f16;
typedef __attribute__((ext_vector_type(2))) f16 f16x2;
typedef __attribute__((ext_vector_type(8))) f16 f16x8;
typedef __attribute__((ext_vector_type(4))) float f32x4;

__device__ __forceinline__ float lrelu(float v) { return v > 0.f ? v : NEG * v; }
__device__ __forceinline__ u16 f2h(float x) { union { u16 s; f16 h; } c; c.h = (f16)x; return c.s; }
__device__ __forceinline__ float h2f(u16 s) { union { u16 s; f16 h; } c; c.s = s; return (float)c.h; }
__device__ __forceinline__ f16x2 u2h2(u32 u) { union { u32 u; f16x2 h; } c; c.u = u; return c.h; }
__device__ __forceinline__ u32 packp(float p) { u32 h = f2h(p); return h | (h << 16); }

// ---------------- BatchNorm stats (f32 input) ----------------
template<int C>
__global__ __launch_bounds__(256) void k_bn_part(const float* __restrict__ x, int rows,
                                                 float* __restrict__ part) {
    const int RPI = 256 / C;
    int col = threadIdx.x % C;
    int sub = threadIdx.x / C;
    int nb = gridDim.x;
    int rpb = (rows + nb - 1) / nb;
    int r0 = blockIdx.x * rpb;
    int r1 = min(rows, r0 + rpb);
    float s = 0.f, q = 0.f;
    for (int r = r0 + sub; r < r1; r += RPI) {
        float v = x[(size_t)r * C + col];
        s += v; q += v * v;
    }
    __shared__ float ls[256], lq[256];
    ls[threadIdx.x] = s; lq[threadIdx.x] = q;
    __syncthreads();
    for (int st = RPI / 2; st > 0; st >>= 1) {
        if (sub < st) {
            ls[threadIdx.x] += ls[threadIdx.x + st * C];
            lq[threadIdx.x] += lq[threadIdx.x + st * C];
        }
        __syncthreads();
    }
    if (sub == 0) {
        part[(size_t)blockIdx.x * C + col] = ls[col];
        part[(size_t)(nb + blockIdx.x) * C + col] = lq[col];
    }
}

// f16-input variant, C=64
__global__ __launch_bounds__(256) void k_bn_part16(const u16* __restrict__ x, int rows,
                                                   float* __restrict__ part) {
    int col = threadIdx.x & 63;
    int sub = threadIdx.x >> 6;
    int nb = gridDim.x;
    int rpb = (rows + nb - 1) / nb;
    int r0 = blockIdx.x * rpb;
    int r1 = min(rows, r0 + rpb);
    float s = 0.f, q = 0.f;
    for (int r = r0 + sub; r < r1; r += 4) {
        float v = h2f(x[(size_t)r * 64 + col]);
        s += v; q += v * v;
    }
    __shared__ float ls[256], lq[256];
    ls[threadIdx.x] = s; lq[threadIdx.x] = q;
    __syncthreads();
    for (int st = 2; st > 0; st >>= 1) {
        if (sub < st) {
            ls[threadIdx.x] += ls[threadIdx.x + st * 64];
            lq[threadIdx.x] += lq[threadIdx.x + st * 64];
        }
        __syncthreads();
    }
    if (sub == 0) {
        part[(size_t)blockIdx.x * 64 + col] = ls[col];
        part[(size_t)(nb + blockIdx.x) * 64 + col] = lq[col];
    }
}

// old small bn_adj (head path only)
__global__ __launch_bounds__(64) void k_bn_adj(const float* __restrict__ part, int nb, int rows, int C,
                                               const float* __restrict__ W, const float* __restrict__ b,
                                               int Ncol, float* __restrict__ sc, float* __restrict__ badj) {
    int c = threadIdx.x;
    __shared__ float shl[64];
    if (c < C) {
        float s = 0.f, q = 0.f;
        for (int bb = 0; bb < nb; bb++) {
            s += part[(size_t)bb * C + c];
            q += part[(size_t)(nb + bb) * C + c];
        }
        float mu = s / rows;
        float var = q / rows - mu * mu;
        float sl = rsqrtf(var + BNEPS);
        sc[c] = sl;
        shl[c] = BNB - mu * sl;
    }
    __syncthreads();
    if (c < Ncol) {
        float a = b ? b[c] : 0.f;
        for (int k = 0; k < C; k++) a += shl[k] * W[(size_t)k * Ncol + c];
        badj[c] = a;
    }
}

// fused: BN stats + badj + f16 MFMA B-fragments with sc folded into W
template<int C>
__global__ __launch_bounds__(256) void k_bnadjf(const float* __restrict__ part, int nb, int rows,
                                                const float* __restrict__ W, const float* __restrict__ b,
                                                float* __restrict__ badj, u16* __restrict__ Bff) {
    int t = threadIdx.x;
    int c = t & 63, seg = t >> 6;
    __shared__ float rs[4][64], rq[4][64];
    __shared__ float scl[64], shl[64];
    float s = 0.f, q = 0.f;
    if (c < C)
        for (int bb = seg; bb < nb; bb += 4) {
            s += part[(size_t)bb * C + c];
            q += part[(size_t)(nb + bb) * C + c];
        }
    rs[seg][c] = s; rq[seg][c] = q;
    __syncthreads();
    if (t < C) {
        float ss = rs[0][t] + rs[1][t] + rs[2][t] + rs[3][t];
        float qq = rq[0][t] + rq[1][t] + rq[2][t] + rq[3][t];
        float mu = ss / rows;
        float var = qq / rows - mu * mu;
        float sl = rsqrtf(var + BNEPS);
        scl[t] = sl; shl[t] = BNB - mu * sl;
    }
    __syncthreads();
    float a = 0.f;
    for (int k = seg; k < C; k += 4) a += shl[k] * W[(size_t)k * 64 + c];
    rs[seg][c] = a;
    __syncthreads();
    if (t < 64) badj[t] = (b ? b[t] : 0.f) + rs[0][t] + rs[1][t] + rs[2][t] + rs[3][t];
    const int KB = C / 32;
    for (int idx = t; idx < 4 * KB * 64 * 8; idx += 256) {
        int j = idx & 7;
        int lane = (idx >> 3) & 63;
        int kb = (idx >> 9) % KB;
        int ct = idx / (KB * 512);
        int k = kb * 32 + (lane >> 4) * 8 + j;
        int col = ct * 16 + (lane & 15);
        Bff[idx] = f2h(scl[k] * W[(size_t)k * 64 + col]);
    }
}

// ---------------- MFMA node GEMM ----------------
template<int KB, int EPI, bool F32IN>
__global__ __launch_bounds__(256) void k_gemm_mf(const void* __restrict__ xin,
                                                 const u16* __restrict__ Bff,
                                                 const float* __restrict__ badj,
                                                 u16* __restrict__ outb, int rows,
                                                 const float* __restrict__ att, float* __restrict__ hs,
                                                 const float* __restrict__ as_, const float* __restrict__ ad_,
                                                 float* __restrict__ asrc, float* __restrict__ adst) {
    int wid = threadIdx.x >> 6, lane = threadIdx.x & 63;
    int er = lane & 15, kh = lane >> 4;
    int r0 = blockIdx.x * 64;
    int rw = r0 + wid * 16;
    __shared__ u16 Dl[64][68];
    f16x8 bf[4][KB];
#pragma unroll
    for (int ct = 0; ct < 4; ct++)
#pragma unroll
        for (int kb = 0; kb < KB; kb++)
            bf[ct][kb] = *(const f16x8*)(Bff + ((size_t)(ct * KB + kb) * 64 + lane) * 8);
    f16x8 af[KB];
    int arow = rw + er;
    if (F32IN) {
        const float* xf = (const float*)xin;
        f16x8 av = (f16x8)(f16)0.f;
        if (arow < rows) {
            const float4* p = (const float4*)(xf + (size_t)arow * 32 + kh * 8);
            float4 v0 = p[0], v1 = p[1];
            av[0] = (f16)v0.x; av[1] = (f16)v0.y; av[2] = (f16)v0.z; av[3] = (f16)v0.w;
            av[4] = (f16)v1.x; av[5] = (f16)v1.y; av[6] = (f16)v1.z; av[7] = (f16)v1.w;
        }
        af[0] = av;
    } else {
        const u16* xh = (const u16*)xin;
#pragma unroll
        for (int kb = 0; kb < KB; kb++) {
            f16x8 av = (f16x8)(f16)0.f;
            if (arow < rows) av = *(const f16x8*)(xh + (size_t)arow * 64 + kb * 32 + kh * 8);
            af[kb] = av;
        }
    }
    f32x4 d[4];
#pragma unroll
    for (int ct = 0; ct < 4; ct++) {
        float bj = badj[ct * 16 + er];
        f32x4 cc = {bj, bj, bj, bj};
#pragma unroll
        for (int kb = 0; kb < KB; kb++)
            cc = __builtin_amdgcn_mfma_f32_16x16x32_f16(af[kb], bf[ct][kb], cc, 0, 0, 0);
        d[ct] = cc;
    }
#pragma unroll
    for (int ct = 0; ct < 4; ct++)
#pragma unroll
        for (int r = 0; r < 4; r++)
            Dl[wid * 16 + kh * 4 + r][ct * 16 + er] = f2h(d[ct][r]);
    if (EPI == 1) {
        float av[4];
#pragma unroll
        for (int ct = 0; ct < 4; ct++) av[ct] = att[ct * 16 + er];
#pragma unroll
        for (int r = 0; r < 4; r++) {
            float v = d[0][r] * av[0] + d[1][r] * av[1] + d[2][r] * av[2] + d[3][r] * av[3];
#pragma unroll
            for (int o = 1; o < 16; o <<= 1) v += __shfl_xor(v, o);
            int rr = rw + kh * 4 + r;
            if (er == 0 && rr < rows) hs[rr] = v;
        }
    }
    if (EPI == 2) {
        float a1v[4], a2v[4];
#pragma unroll
        for (int ct = 0; ct < 4; ct++) { a1v[ct] = as_[ct * 16 + er]; a2v[ct] = ad_[ct * 16 + er]; }
#pragma unroll
        for (int ct = 0; ct < 4; ct++) {
#pragma unroll
            for (int r = 0; r < 4; r++) {
                float s1 = d[ct][r] * a1v[ct], s2 = d[ct][r] * a2v[ct];
#pragma unroll
                for (int o = 1; o < 16; o <<= 1) { s1 += __shfl_xor(s1, o); s2 += __shfl_xor(s2, o); }
                int rr = rw + kh * 4 + r;
                if (er == 0 && rr < rows) {
                    asrc[(size_t)rr * 4 + ct] = s1;
                    adst[(size_t)rr * 4 + ct] = s2;
                }
            }
        }
    }
    __syncthreads();
    const u32* D32 = (const u32*)&Dl[0][0];
    u32* out32 = (u32*)outb;
    for (int idx = threadIdx.x; idx < 64 * 32; idx += 256) {
        int r = idx >> 5, c2 = idx & 31;
        int rr = r0 + r;
        if (rr < rows) out32[(size_t)rr * 32 + c2] = D32[r * 34 + c2];
    }
}

// ---------------- head GEMM (f32, small) ----------------
__global__ __launch_bounds__(256) void k_gemm_head(const float* __restrict__ x, const float* __restrict__ W,
                                                   const float* __restrict__ sc, const float* __restrict__ badj,
                                                   float* __restrict__ outf, int rows) {
    __shared__ float Ws[64 * 64];
    __shared__ float Xs[32 * 64];
    int r0 = blockIdx.x * 32;
    for (int i = threadIdx.x; i < 64 * 64; i += 256) Ws[i] = W[i];
    for (int i = threadIdx.x; i < 32 * 64; i += 256) {
        int r = i / 64, k = i % 64;
        int rr = r0 + r;
        Xs[i] = (rr < rows) ? x[(size_t)rr * 64 + k] * sc[k] : 0.f;
    }
    __syncthreads();
    int col = threadIdx.x & 63;
    int rg = threadIdx.x >> 6;
    float b0 = badj[col];
    float acc[8];
#pragma unroll
    for (int i = 0; i < 8; i++) acc[i] = b0;
    for (int k = 0; k < 64; k++) {
        float w = Ws[k * 64 + col];
#pragma unroll
        for (int i = 0; i < 8; i++) acc[i] += Xs[(rg * 8 + i) * 64 + k] * w;
    }
#pragma unroll
    for (int i = 0; i < 8; i++) {
        int r = r0 + rg * 8 + i;
        if (r < rows) outf[(size_t)r * 64 + col] = fmaxf(acc[i], 0.f);
    }
}

// folded attention weights + edgepre MFMA B-fragments
__global__ __launch_bounds__(768) void k_we(const float* __restrict__ cWe, const float* __restrict__ cae,
                                            const float* __restrict__ Wee, const float* __restrict__ att,
                                            const float* __restrict__ bee, float* __restrict__ wEbuf,
                                            u16* __restrict__ Bf1, u16* __restrict__ Bf2) {
    int t = threadIdx.x;
    int l = t >> 8;
    int h = (t >> 6) & 3;
    int k = t & 63;
    float a = 0.f;
    for (int d = 0; d < 16; d++)
        a += cWe[(size_t)l * 4096 + k * 64 + h * 16 + d] * cae[l * 64 + h * 16 + d];
    wEbuf[t] = a;
    if (t < 16) {
        float v = 0.f;
        for (int j = 0; j < 64; j++) v += Wee[t * 64 + j] * att[j];
        wEbuf[768 + t] = v;
    }
    if (t == 16) {
        float v = 0.f;
        for (int j = 0; j < 64; j++) v += bee[j] * att[j];
        wEbuf[784] = v;
    }
    for (int idx = t; idx < 4 * 64 * 8; idx += 768) {
        int cb = idx >> 9, ln = (idx >> 3) & 63, j = idx & 7;
        int col = cb * 16 + (ln & 15);
        int kk = (ln >> 4) * 8 + j;
        float v = (kk < 16) ? Wee[kk * 64 + col] : 0.f;
        Bf1[idx] = f2h(v);
    }
    __syncthreads();
    for (int idx = t; idx < 2 * 64 * 8; idx += 768) {
        int kb = idx >> 9, ln = (idx >> 3) & 63, j = idx & 7;
        int n = ln & 15;
        int kk = kb * 32 + (ln >> 4) * 8 + j;
        float v = (n < 12) ? wEbuf[n * 64 + kk] : 0.f;
        Bf2[idx] = f2h(v);
    }
}

// ---------------- CSR build via LDS counting sort ----------------
__global__ __launch_bounds__(256) void k_bhist(const int* __restrict__ dst, int* __restrict__ hist) {
    __shared__ int lh[512];
    int t = threadIdx.x;
    lh[t] = 0; lh[t + 256] = 0;
    __syncthreads();
    int base = blockIdx.x * CHUNK2;
    int cnt = min(CHUNK2, NE - base);
    for (int i = t; i < cnt; i += 256) atomicAdd(&lh[dst[base + i] >> 8], 1);
    __syncthreads();
    for (int b = t; b < NBUK; b += 256) hist[blockIdx.x * NBUK + b] = lh[b];
}

__global__ __launch_bounds__(256) void k_colsum(const int* __restrict__ hist, int* __restrict__ colsum) {
    int col = blockIdx.x;
    int t = threadIdx.x;
    int s = 0;
    for (int b = t; b < NB2; b += 256) s += hist[b * NBUK + col];
    __shared__ int ls[256];
    ls[t] = s;
    __syncthreads();
    for (int st = 128; st; st >>= 1) {
        if (t < st) ls[t] += ls[t + st];
        __syncthreads();
    }
    if (t == 0) colsum[col] = ls[0];
}

__global__ __launch_bounds__(512) void k_bukscan(const int* __restrict__ colsum,
                                                 int* __restrict__ bucketBase, int* __restrict__ rowp) {
    __shared__ int ls[512];
    int t = threadIdx.x;
    int v = (t < NBUK) ? colsum[t] : 0;
    ls[t] = v;
    __syncthreads();
    for (int off = 1; off < 512; off <<= 1) {
        int a = (t >= off) ? ls[t - off] : 0;
        __syncthreads();
        ls[t] += a;
        __syncthreads();
    }
    if (t < NBUK) bucketBase[t] = ls[t] - v;
    if (t == 0) { bucketBase[NBUK] = NE; rowp[NN] = NE; }
}

__global__ __launch_bounds__(512) void k_coloffs(const int* __restrict__ hist,
                                                 const int* __restrict__ bucketBase, int* __restrict__ offs) {
    int col = blockIdx.x;
    int t = threadIdx.x;
    __shared__ int ls[512];
    int v = (t < NB2) ? hist[(size_t)t * NBUK + col] : 0;
    ls[t] = v;
    __syncthreads();
    for (int off = 1; off < 512; off <<= 1) {
        int a = (t >= off) ? ls[t - off] : 0;
        __syncthreads();
        ls[t] += a;
        __syncthreads();
    }
    if (t < NB2) offs[(size_t)t * NBUK + col] = bucketBase[col] + ls[t] - v;
}

__global__ __launch_bounds__(256) void k_part(const int* __restrict__ src, const int* __restrict__ dst,
                                              const int* __restrict__ offs, int2* __restrict__ seTmp) {
    __shared__ int lhist[512];
    __shared__ int lstart[NBUK + 1];
    __shared__ int lcur[NBUK];
    __shared__ int loffs[NBUK];
    __shared__ int2 stage[CHUNK2];
    int t = threadIdx.x;
    int base = blockIdx.x * CHUNK2;
    int cnt = min(CHUNK2, NE - base);
    int blkrow = blockIdx.x * NBUK;
    lhist[t] = 0; lhist[t + 256] = 0;
    __syncthreads();
    for (int i = t; i < cnt; i += 256) atomicAdd(&lhist[dst[base + i] >> 8], 1);
    __syncthreads();
    for (int off = 1; off < 512; off <<= 1) {
        int v0 = (t >= off) ? lhist[t - off] : 0;
        int v1 = lhist[t + 256 - off];
        __syncthreads();
        lhist[t] += v0; lhist[t + 256] += v1;
        __syncthreads();
    }
    if (t == 0) lstart[0] = 0;
    lstart[t + 1] = lhist[t];
    if (t + 257 <= NBUK) lstart[t + 257] = lhist[t + 256];
    __syncthreads();
    for (int b = t; b < NBUK; b += 256) {
        lcur[b] = lstart[b];
        loffs[b] = offs[blkrow + b];
    }
    __syncthreads();
    for (int i = t; i < cnt; i += 256) {
        int e = base + i;
        int d = dst[e];
        int b = d >> 8;
        int pos = atomicAdd(&lcur[b], 1);
        int2 v; v.x = src[e] | (b << 17); v.y = e | ((d & 255) << 21);
        stage[pos] = v;
    }
    __syncthreads();
    for (int q = t; q < cnt; q += 256) {
        int2 v = stage[q];
        int b = ((u32)v.x) >> 17;
        int2 o; o.x = v.x & 0x1FFFF; o.y = v.y;
        seTmp[loffs[b] + (q - lstart[b])] = o;
    }
}

__global__ __launch_bounds__(256) void k_bucket(const int2* __restrict__ seTmp,
                                                const int* __restrict__ bucketBase,
                                                int2* __restrict__ se, int* __restrict__ rowp) {
    int b = blockIdx.x;
    int t = threadIdx.x;
    int beg = bucketBase[b], end = bucketBase[b + 1];
    int cnt = end - beg;
    __shared__ int lhist[256], lscan[256], lcur[256];
    __shared__ int2 ebuf[CAP3];
    lhist[t] = 0;
    __syncthreads();
    for (int i = t; i < cnt; i += 256)
        atomicAdd(&lhist[((u32)seTmp[beg + i].y) >> 21], 1);
    __syncthreads();
    lscan[t] = lhist[t];
    __syncthreads();
    for (int off = 1; off < 256; off <<= 1) {
        int v = (t >= off) ? lscan[t - off] : 0;
        __syncthreads();
        lscan[t] += v;
        __syncthreads();
    }
    int excl = lscan[t] - lhist[t];
    lcur[t] = excl;
    int node = b * 256 + t;
    if (node < NN) rowp[node] = beg + excl;
    __syncthreads();
    if (cnt <= CAP3) {
        for (int i = t; i < cnt; i += 256) {
            int2 v = seTmp[beg + i];
            int dl = ((u32)v.y) >> 21;
            int pos = atomicAdd(&lcur[dl], 1);
            int2 o; o.x = v.x; o.y = v.y & 0x1FFFFF;
            ebuf[pos] = o;
        }
        __syncthreads();
        for (int q = t; q < cnt; q += 256) se[beg + q] = ebuf[q];
    } else {
        for (int i = t; i < cnt; i += 256) {
            int2 v = seTmp[beg + i];
            int dl = ((u32)v.y) >> 21;
            int pos = atomicAdd(&lcur[dl], 1);
            int2 o; o.x = v.x; o.y = v.y & 0x1FFFFF;
            se[beg + pos] = o;
        }
    }
}

// ---------------- edge precompute via MFMA: 32 edges/wave ----------------
__global__ __launch_bounds__(256) void k_edgepre(const float* __restrict__ ea,
                                                 const u16* __restrict__ Bf1, const u16* __restrict__ Bf2,
                                                 const float* __restrict__ bee, const float* __restrict__ wEbuf,
                                                 const int2* __restrict__ se,
                                                 float* __restrict__ heatt, ushort4* __restrict__ aedH) {
    int wid = threadIdx.x >> 6, lane = threadIdx.x & 63;
    int p0 = (blockIdx.x * 4 + wid) * 32;
    __shared__ f16 EaD[4][32][24];
    __shared__ f16 Pl[4][32][72];
    f16x8 bf1[4], bf2[2];
#pragma unroll
    for (int cb = 0; cb < 4; cb++) bf1[cb] = *(const f16x8*)(Bf1 + ((size_t)cb * 64 + lane) * 8);
#pragma unroll
    for (int kb = 0; kb < 2; kb++) bf2[kb] = *(const f16x8*)(Bf2 + ((size_t)kb * 64 + lane) * 8);
    int e = lane & 31, q = lane >> 5;
    int ei = se[p0 + e].y;
    const float4* pa = (const float4*)(ea + (size_t)ei * 16 + q * 8);
    float4 v0 = pa[0], v1 = pa[1];
    {
        const float* va = wEbuf + 768 + q * 8;
        float part = v0.x * va[0] + v0.y * va[1] + v0.z * va[2] + v0.w * va[3]
                   + v1.x * va[4] + v1.y * va[5] + v1.z * va[6] + v1.w * va[7];
        float po = __shfl_xor(part, 32);
        if (lane < 32) heatt[p0 + e] = part + po + wEbuf[784];
    }
    {
        f16x8 t;
        t[0] = (f16)v0.x; t[1] = (f16)v0.y; t[2] = (f16)v0.z; t[3] = (f16)v0.w;
        t[4] = (f16)v1.x; t[5] = (f16)v1.y; t[6] = (f16)v1.z; t[7] = (f16)v1.w;
        *(f16x8*)&EaD[wid][e][q * 8] = t;
    }
    __builtin_amdgcn_wave_barrier();
    int er = lane & 15, kh = lane >> 4;
    f16x8 a0f = (f16x8)(f16)0.f, a1f = (f16x8)(f16)0.f;
    if (kh < 2) {
        a0f = *(const f16x8*)&EaD[wid][er][kh * 8];
        a1f = *(const f16x8*)&EaD[wid][16 + er][kh * 8];
    }
    f32x4 z = {0.f, 0.f, 0.f, 0.f};
    f32x4 d0[4], d1[4];
#pragma unroll
    for (int ct = 0; ct < 4; ct++) {
        d0[ct] = __builtin_amdgcn_mfma_f32_16x16x32_f16(a0f, bf1[ct], z, 0, 0, 0);
        d1[ct] = __builtin_amdgcn_mfma_f32_16x16x32_f16(a1f, bf1[ct], z, 0, 0, 0);
    }
    {
#pragma unroll
        for (int ct = 0; ct < 4; ct++) {
            float bb = bee[ct * 16 + er];
#pragma unroll
            for (int r = 0; r < 4; r++) {
                Pl[wid][kh * 4 + r][ct * 16 + er] = (f16)fmaxf(d0[ct][r] + bb, 0.f);
                Pl[wid][16 + kh * 4 + r][ct * 16 + er] = (f16)fmaxf(d1[ct][r] + bb, 0.f);
            }
        }
    }
    __builtin_amdgcn_wave_barrier();
    f16x8 pa00 = *(const f16x8*)&Pl[wid][er][kh * 8];
    f16x8 pa01 = *(const f16x8*)&Pl[wid][er][32 + kh * 8];
    f16x8 pa10 = *(const f16x8*)&Pl[wid][16 + er][kh * 8];
    f16x8 pa11 = *(const f16x8*)&Pl[wid][16 + er][32 + kh * 8];
    f32x4 dd0 = __builtin_amdgcn_mfma_f32_16x16x32_f16(pa00, bf2[0], z, 0, 0, 0);
    dd0 = __builtin_amdgcn_mfma_f32_16x16x32_f16(pa01, bf2[1], dd0, 0, 0, 0);
    f32x4 dd1 = __builtin_amdgcn_mfma_f32_16x16x32_f16(pa10, bf2[0], z, 0, 0, 0);
    dd1 = __builtin_amdgcn_mfma_f32_16x16x32_f16(pa11, bf2[1], dd1, 0, 0, 0);
    __builtin_amdgcn_wave_barrier();
#pragma unroll
    for (int r = 0; r < 4; r++) {
        EaD[wid][kh * 4 + r][er] = (f16)dd0[r];
        EaD[wid][16 + kh * 4 + r][er] = (f16)dd1[r];
    }
    __builtin_amdgcn_wave_barrier();
    {
        int e2 = lane & 31, l3 = lane >> 5;
        ushort4 o = *(const ushort4*)&EaD[wid][e2][l3 * 4];
        aedH[(size_t)l3 * NE + p0 + e2] = o;
        if (lane < 32) {
            ushort4 o2 = *(const ushort4*)&EaD[wid][lane][8];
            aedH[(size_t)2 * NE + p0 + lane] = o2;
        }
    }
}

// ---------------- EGAT aggregation: 4 cols/lane, packed f16 pk_fma gather ----------------
__global__ __launch_bounds__(256) void k_egat_agg(const int* __restrict__ rowp, const int2* __restrict__ se,
                                                  const float* __restrict__ heatt, const float* __restrict__ hs,
                                                  const u16* __restrict__ hb, u16* __restrict__ xout) {
    int wid = threadIdx.x >> 6, lane = threadIdx.x & 63;
    int n = blockIdx.x * 4 + wid;
    if (n >= NN) return;
    int beg = rowp[n], deg = rowp[n + 1] - beg;
    if (deg == 0) { xout[(size_t)n * 64 + lane] = 0; return; }
    float hsn = hs[n];
    __shared__ u32 plp[4][64];
    __shared__ int soff[4][64];
    if (deg <= 64) {
        int s = 0; float lg = MNEG;
        if (lane < deg) {
            int2 pr = se[beg + lane];
            s = pr.x;
            lg = lrelu(hs[s] + hsn + heatt[beg + lane]);
        }
        float m = lg;
#pragma unroll
        for (int o = 32; o; o >>= 1) m = fmaxf(m, __shfl_xor(m, o));
        float e = (lane < deg) ? __expf(lg - m) : 0.f;
        float sm = e;
#pragma unroll
        for (int o = 32; o; o >>= 1) sm += __shfl_xor(sm, o);
        float p = e * (1.f / sm);
        plp[wid][lane] = packp(p);
        soff[wid][lane] = s << 7;   // s * 128 bytes
        __builtin_amdgcn_wave_barrier();
        int cq = lane & 15, q = lane >> 4;
        const u32* prow = &plp[wid][0];
        const int* srow = &soff[wid][0];
        const char* hp = (const char*)hb + cq * 8;
        f16x2 a01a = (f16x2)(f16)0.f, a23a = (f16x2)(f16)0.f;
        f16x2 a01b = (f16x2)(f16)0.f, a23b = (f16x2)(f16)0.f;
        for (int j = 0; j < deg; j += 8) {
            int e0 = j + q, e1 = j + 4 + q;
            u32 pp0 = prow[e0]; int o0 = srow[e0];
            u32 pp1 = prow[e1]; int o1 = srow[e1];
            uint2 w0 = *(const uint2*)(hp + o0);
            uint2 w1 = *(const uint2*)(hp + o1);
            f16x2 q0 = u2h2(pp0), q1 = u2h2(pp1);
            a01a = q0 * u2h2(w0.x) + a01a;
            a23a = q0 * u2h2(w0.y) + a23a;
            a01b = q1 * u2h2(w1.x) + a01b;
            a23b = q1 * u2h2(w1.y) + a23b;
        }
        float c0 = (float)a01a[0] + (float)a01b[0];
        float c1 = (float)a01a[1] + (float)a01b[1];
        float c2 = (float)a23a[0] + (float)a23b[0];
        float c3 = (float)a23a[1] + (float)a23b[1];
        c0 += __shfl_xor(c0, 16); c0 += __shfl_xor(c0, 32);
        c1 += __shfl_xor(c1, 16); c1 += __shfl_xor(c1, 32);
        c2 += __shfl_xor(c2, 16); c2 += __shfl_xor(c2, 32);
        c3 += __shfl_xor(c3, 16); c3 += __shfl_xor(c3, 32);
        if (lane < 16) {
            ushort4 o;
            o.x = f2h(fmaxf(c0, 0.f));
            o.y = f2h(fmaxf(c1, 0.f));
            o.z = f2h(fmaxf(c2, 0.f));
            o.w = f2h(fmaxf(c3, 0.f));
            *(ushort4*)(xout + (size_t)n * 64 + cq * 4) = o;
        }
    } else {
        float m = MNEG, sm = 0.f;
        for (int i = lane; i < deg; i += 64) {
            int2 pr = se[beg + i];
            float v = lrelu(hs[pr.x] + hsn + heatt[beg + i]);
            float mn = fmaxf(m, v);
            sm = sm * __expf(m - mn) + __expf(v - mn);
            m = mn;
        }
#pragma unroll
        for (int o = 32; o; o >>= 1) {
            float mo = __shfl_xor(m, o), so = __shfl_xor(sm, o);
            float mn = fmaxf(m, mo);
            sm = sm * __expf(m - mn) + so * __expf(mo - mn);
            m = mn;
        }
        float inv = 1.f / sm;
        float acc0 = 0.f;
        for (int base = 0; base < deg; base += 64) {
            int i = base + lane;
            int s = 0; float p = 0.f;
            if (i < deg) {
                int2 pr = se[beg + i];
                s = pr.x;
                p = __expf(lrelu(hs[s] + hsn + heatt[beg + i]) - m) * inv;
            }
            int mm = min(64, deg - base);
            for (int j = 0; j < mm; j++) {
                int s0 = __shfl(s, j); float q0 = __shfl(p, j);
                acc0 = fmaf(q0, h2f(hb[(size_t)s0 * 64 + lane]), acc0);
            }
        }
        xout[(size_t)n * 64 + lane] = f2h(fmaxf(acc0, 0.f));
    }
}

// ---------------- conv aggregation: 4 cols/lane, packed f16 pk_fma gather (padded LDS) ----------------
__global__ __launch_bounds__(256) void k_conv_agg(const int* __restrict__ rowp, const int2* __restrict__ se,
                                                  const ushort4* __restrict__ aedH, const float* __restrict__ asrc,
                                                  const float* __restrict__ adst, const u16* __restrict__ hb,
                                                  const float* __restrict__ bias, u16* __restrict__ xout) {
    int wid = threadIdx.x >> 6, lane = threadIdx.x & 63;
    int n = blockIdx.x * 4 + wid;
    if (n >= NN) return;
    int beg = rowp[n], deg = rowp[n + 1] - beg;
    if (deg == 0) { xout[(size_t)n * 64 + lane] = f2h(fmaxf(bias[lane], 0.f)); return; }
    float4 an = ((const float4*)adst)[n];
    // stride 65: bank(h*65+e) = (h+e)%32 -> 4 head rows hit distinct banks (R9 had stride 64 -> 4-way conflict)
    __shared__ u32 plp[4][4][65];
    __shared__ int soff[4][64];
    __shared__ float plsF[4][4][72];
    __shared__ int slF[4][64];
    if (deg <= 64) {
        int s = 0;
        float l0 = MNEG, l1 = MNEG, l2 = MNEG, l3 = MNEG;
        if (lane < deg) {
            s = se[beg + lane].x;
            float4 as4 = ((const float4*)asrc)[s];
            ushort4 u = aedH[beg + lane];
            l0 = lrelu(as4.x + an.x + h2f(u.x));
            l1 = lrelu(as4.y + an.y + h2f(u.y));
            l2 = lrelu(as4.z + an.z + h2f(u.z));
            l3 = lrelu(as4.w + an.w + h2f(u.w));
        }
        float m0 = l0, m1 = l1, m2 = l2, m3 = l3;
#pragma unroll
        for (int o = 32; o; o >>= 1) {
            m0 = fmaxf(m0, __shfl_xor(m0, o)); m1 = fmaxf(m1, __shfl_xor(m1, o));
            m2 = fmaxf(m2, __shfl_xor(m2, o)); m3 = fmaxf(m3, __shfl_xor(m3, o));
        }
        float e0 = (lane < deg) ? __expf(l0 - m0) : 0.f;
        float e1 = (lane < deg) ? __expf(l1 - m1) : 0.f;
        float e2 = (lane < deg) ? __expf(l2 - m2) : 0.f;
        float e3 = (lane < deg) ? __expf(l3 - m3) : 0.f;
        float s0 = e0, s1 = e1, s2 = e2, s3 = e3;
#pragma unroll
        for (int o = 32; o; o >>= 1) {
            s0 += __shfl_xor(s0, o); s1 += __shfl_xor(s1, o);
            s2 += __shfl_xor(s2, o); s3 += __shfl_xor(s3, o);
        }
        plp[wid][0][lane] = packp(e0 * (1.f / s0));
        plp[wid][1][lane] = packp(e1 * (1.f / s1));
        plp[wid][2][lane] = packp(e2 * (1.f / s2));
        plp[wid][3][lane] = packp(e3 * (1.f / s3));
        soff[wid][lane] = s << 7;
        __builtin_amdgcn_wave_barrier();
        int cq = lane & 15, q = lane >> 4;
        const u32* prow = &plp[wid][cq >> 2][0];
        const int* srow = &soff[wid][0];
        const char* hp = (const char*)hb + cq * 8;
        f16x2 a01a = (f16x2)(f16)0.f, a23a = (f16x2)(f16)0.f;
        f16x2 a01b = (f16x2)(f16)0.f, a23b = (f16x2)(f16)0.f;
        for (int j = 0; j < deg; j += 8) {
            int e0i = j + q, e1i = j + 4 + q;
            u32 pp0 = prow[e0i]; int o0 = srow[e0i];
            u32 pp1 = prow[e1i]; int o1 = srow[e1i];
            uint2 w0 = *(const uint2*)(hp + o0);
            uint2 w1 = *(const uint2*)(hp + o1);
            f16x2 q0 = u2h2(pp0), q1 = u2h2(pp1);
            a01a = q0 * u2h2(w0.x) + a01a;
            a23a = q0 * u2h2(w0.y) + a23a;
            a01b = q1 * u2h2(w1.x) + a01b;
            a23b = q1 * u2h2(w1.y) + a23b;
        }
        float c0 = (float)a01a[0] + (float)a01b[0];
        float c1 = (float)a01a[1] + (float)a01b[1];
        float c2 = (float)a23a[0] + (float)a23b[0];
        float c3 = (float)a23a[1] + (float)a23b[1];
        c0 += __shfl_xor(c0, 16); c0 += __shfl_xor(c0, 32);
        c1 += __shfl_xor(c1, 16); c1 += __shfl_xor(c1, 32);
        c2 += __shfl_xor(c2, 16); c2 += __shfl_xor(c2, 32);
        c3 += __shfl_xor(c3, 16); c3 += __shfl_xor(c3, 32);
        if (lane < 16) {
            ushort4 o;
            o.x = f2h(fmaxf(c0 + bias[cq * 4 + 0], 0.f));
            o.y = f2h(fmaxf(c1 + bias[cq * 4 + 1], 0.f));
            o.z = f2h(fmaxf(c2 + bias[cq * 4 + 2], 0.f));
            o.w = f2h(fmaxf(c3 + bias[cq * 4 + 3], 0.f));
            *(ushort4*)(xout + (size_t)n * 64 + cq * 4) = o;
        }
    } else {
        int hq = lane >> 4;
        float m0 = MNEG, m1 = MNEG, m2 = MNEG, m3 = MNEG;
        float s0 = 0.f, s1 = 0.f, s2 = 0.f, s3 = 0.f;
        for (int i = lane; i < deg; i += 64) {
            int s = se[beg + i].x;
            float4 as4 = ((const float4*)asrc)[s];
            ushort4 u = aedH[beg + i];
            float l0 = lrelu(as4.x + an.x + h2f(u.x));
            float l1 = lrelu(as4.y + an.y + h2f(u.y));
            float l2 = lrelu(as4.z + an.z + h2f(u.z));
            float l3 = lrelu(as4.w + an.w + h2f(u.w));
            float n0 = fmaxf(m0, l0); s0 = s0 * __expf(m0 - n0) + __expf(l0 - n0); m0 = n0;
            float n1 = fmaxf(m1, l1); s1 = s1 * __expf(m1 - n1) + __expf(l1 - n1); m1 = n1;
            float n2 = fmaxf(m2, l2); s2 = s2 * __expf(m2 - n2) + __expf(l2 - n2); m2 = n2;
            float n3 = fmaxf(m3, l3); s3 = s3 * __expf(m3 - n3) + __expf(l3 - n3); m3 = n3;
        }
#pragma unroll
        for (int o = 32; o; o >>= 1) {
            float mo, so, mn;
            mo = __shfl_xor(m0, o); so = __shfl_xor(s0, o); mn = fmaxf(m0, mo);
            s0 = s0 * __expf(m0 - mn) + so * __expf(mo - mn); m0 = mn;
            mo = __shfl_xor(m1, o); so = __shfl_xor(s1, o); mn = fmaxf(m1, mo);
            s1 = s1 * __expf(m1 - mn) + so * __expf(mo - mn); m1 = mn;
            mo = __shfl_xor(m2, o); so = __shfl_xor(s2, o); mn = fmaxf(m2, mo);
            s2 = s2 * __expf(m2 - mn) + so * __expf(mo - mn); m2 = mn;
            mo = __shfl_xor(m3, o); so = __shfl_xor(s3, o); mn = fmaxf(m3, mo);
            s3 = s3 * __expf(m3 - mn) + so * __expf(mo - mn); m3 = mn;
        }
        float i0 = 1.f / s0, i1 = 1.f / s1, i2 = 1.f / s2, i3 = 1.f / s3;
        float acc0 = 0.f;
        for (int base = 0; base < deg; base += 64) {
            int i = base + lane;
            if (i < deg) {
                int s = se[beg + i].x;
                float4 as4 = ((const float4*)asrc)[s];
                ushort4 u = aedH[beg + i];
                plsF[wid][0][lane] = __expf(lrelu(as4.x + an.x + h2f(u.x)) - m0) * i0;
                plsF[wid][1][lane] = __expf(lrelu(as4.y + an.y + h2f(u.y)) - m1) * i1;
                plsF[wid][2][lane] = __expf(lrelu(as4.z + an.z + h2f(u.z)) - m2) * i2;
                plsF[wid][3][lane] = __expf(lrelu(as4.w + an.w + h2f(u.w)) - m3) * i3;
                slF[wid][lane] = s;
            }
            __builtin_amdgcn_wave_barrier();
            int mm = min(64, deg - base);
            const float* prow = &plsF[wid][hq][0];
            const int* srow = &slF[wid][0];
            for (int j = 0; j < mm; j++)
                acc0 = fmaf(prow[j], h2f(hb[(size_t)srow[j] * 64 + lane]), acc0);
            __builtin_amdgcn_wave_barrier();
        }
        xout[(size_t)n * 64 + lane] = f2h(fmaxf(acc0 + bias[lane], 0.f));
    }
}

// ---------------- pool + head ----------------
__device__ __forceinline__ int lowerb(const int* a, int n, int key) {
    int lo = 0, hi = n;
    while (lo < hi) {
        int mid = (lo + hi) >> 1;
        if (a[mid] < key) lo = mid + 1; else hi = mid;
    }
    return lo;
}

__global__ __launch_bounds__(256) void k_pool(const u16* __restrict__ x, const int* __restrict__ batch,
                                              float* __restrict__ g) {
    int gr = blockIdx.x;
    int lane = threadIdx.x & 63;
    int sub = threadIdx.x >> 6;
    int beg = lowerb(batch, NN, gr);
    int end = lowerb(batch, NN, gr + 1);
    float acc = 0.f;
    for (int i = beg + sub; i < end; i += 4) acc += h2f(x[(size_t)i * 64 + lane]);
    __shared__ float ls[4][64];
    ls[sub][lane] = acc;
    __syncthreads();
    if (sub == 0)
        g[(size_t)gr * 64 + lane] = ls[0][lane] + ls[1][lane] + ls[2][lane] + ls[3][lane];
}

__global__ __launch_bounds__(64) void k_cls(const float* __restrict__ y, const float* __restrict__ W,
                                            const float* __restrict__ sc, const float* __restrict__ badj,
                                            float* __restrict__ out) {
    int r = blockIdx.x, lane = threadIdx.x;
    __shared__ float yr[64];
    yr[lane] = y[(size_t)r * 64 + lane] * sc[lane];
    __syncthreads();
    float lg = -INFINITY;
    if (lane < NCLS) {
        float a = badj[lane];
        for (int k = 0; k < 64; k++) a += yr[k] * W[k * NCLS + lane];
        lg = a;
    }
    float mx = lg;
#pragma unroll
    for (int o = 32; o; o >>= 1) mx = fmaxf(mx, __shfl_xor(mx, o));
    float e = (lane < NCLS) ? expf(lg - mx) : 0.f;
    float s = e;
#pragma unroll
    for (int o = 32; o; o >>= 1) s += __shfl_xor(s, o);
    if (lane < NCLS) out[(size_t)r * NCLS + lane] = lg - mx - logf(s);
}

extern "C" void kernel_launch(void* const* d_in, const int* in_sizes, int n_in,
                              void* d_out, int out_size, void* d_ws, size_t ws_size,
                              hipStream_t stream) {
    const float* x0  = (const float*)d_in[0];
    const float* ea  = (const float*)d_in[1];
    const int* eidx  = (const int*)d_in[2];
    const int* batch = (const int*)d_in[3];
    const float* Wx  = (const float*)d_in[4];
    const float* bx  = (const float*)d_in[5];
    const float* Wee = (const float*)d_in[6];
    const float* bee = (const float*)d_in[7];
    const float* att = (const float*)d_in[8];
    const float* cW  = (const float*)d_in[9];
    const float* cWe = (const float*)d_in[10];
    const float* cas = (const float*)d_in[11];
    const float* cad = (const float*)d_in[12];
    const float* cae = (const float*)d_in[13];
    const float* cb  = (const float*)d_in[14];
    const float* lW  = (const float*)d_in[15];
    const float* lb  = (const float*)d_in[16];
    const float* clW = (const float*)d_in[17];
    const float* clb = (const float*)d_in[18];
    float* out = (float*)d_out;

    const int* srcA = eidx;
    const int* dstA = eidx + NE;

    char* w = (char*)d_ws;
    size_t off = 0;
    auto alloc = [&](size_t bytes) -> void* {
        void* p = w + off;
        off += (bytes + 255) & ~(size_t)255;
        return p;
    };
    u16* hbA      = (u16*)alloc((size_t)NN * 64 * 2);
    u16* B16      = (u16*)alloc((size_t)NN * 64 * 2);
    float* hs     = (float*)alloc((size_t)NN * 4);
    float* asrc   = (float*)alloc((size_t)NN * 4 * 4);
    float* adst   = (float*)alloc((size_t)NN * 4 * 4);
    float* heatt  = (float*)alloc((size_t)NE * 4);
    ushort4* aedH = (ushort4*)alloc((size_t)3 * NE * 8);
    int2* se      = (int2*)alloc((size_t)NE * 8);
    int* rowp     = (int*)alloc((size_t)(NN + 1) * 4);
    int* hist     = (int*)alloc((size_t)NB2 * NBUK * 4);
    int* offs     = (int*)alloc((size_t)NB2 * NBUK * 4);
    int* bucketBase = (int*)alloc((size_t)(NBUK + 1) * 4);
    int* colsum   = (int*)alloc((size_t)NBUK * 4);
    float* part   = (float*)alloc((size_t)2 * 200 * 64 * 4);
    float* badj   = (float*)alloc(64 * 4);
    float* wEbuf  = (float*)alloc(800 * 4);
    u16* Bf1      = (u16*)alloc(4 * 64 * 8 * 2);
    u16* Bf2      = (u16*)alloc(2 * 64 * 8 * 2);
    u16* Bff      = (u16*)alloc(8 * 64 * 8 * 2);
    float* g      = (float*)alloc((size_t)NG * 64 * 4);
    float* y      = (float*)alloc((size_t)NG * 64 * 4);
    float* badj2  = (float*)alloc(64 * 4);
    float* badj3  = (float*)alloc(64 * 4);
    float* sc2    = (float*)alloc(64 * 4);
    float* sc3    = (float*)alloc(64 * 4);
    if (off > ws_size) return;

    int2* seTmp = (int2*)aedH;

    const int NB = 200;
    const int GEMMB = (NN + 63) / 64;

    // ---- CSR build ----
    k_bhist<<<NB2, 256, 0, stream>>>(dstA, hist);
    k_colsum<<<NBUK, 256, 0, stream>>>(hist, colsum);
    k_bukscan<<<1, 512, 0, stream>>>(colsum, bucketBase, rowp);
    k_coloffs<<<NBUK, 512, 0, stream>>>(hist, bucketBase, offs);
    k_part<<<NB2, 256, 0, stream>>>(srcA, dstA, offs, seTmp);
    k_bucket<<<NBUK, 256, 0, stream>>>(seTmp, bucketBase, se, rowp);

    // ---- folded attention weights ----
    k_we<<<1, 768, 0, stream>>>(cWe, cae, Wee, att, bee, wEbuf, Bf1, Bf2);

    // ---- BN(x0) + EGAT node GEMM ----
    k_bn_part<32><<<NB, 256, 0, stream>>>(x0, NN, part);
    k_bnadjf<32><<<1, 256, 0, stream>>>(part, NB, NN, Wx, bx, badj, Bff);
    k_gemm_mf<1, 1, true><<<GEMMB, 256, 0, stream>>>(
        x0, Bff, badj, hbA, NN, att, hs, nullptr, nullptr, nullptr, nullptr);

    // ---- edge precompute ----
    k_edgepre<<<NE / 128, 256, 0, stream>>>(ea, Bf1, Bf2, bee, wEbuf, se, heatt, aedH);

    // ---- EGAT aggregation ----
    k_egat_agg<<<(NN + 3) / 4, 256, 0, stream>>>(rowp, se, heatt, hs, hbA, B16);

    // ---- 3 GATConv layers ----
    for (int l = 0; l < 3; l++) {
        k_bn_part16<<<NB, 256, 0, stream>>>(B16, NN, part);
        k_bnadjf<64><<<1, 256, 0, stream>>>(part, NB, NN, cW + (size_t)l * 4096, nullptr, badj, Bff);
        k_gemm_mf<2, 2, false><<<GEMMB, 256, 0, stream>>>(
            B16, Bff, badj, hbA, NN, nullptr, nullptr,
            cas + l * 64, cad + l * 64, asrc, adst);
        k_conv_agg<<<(NN + 3) / 4, 256, 0, stream>>>(rowp, se, aedH + (size_t)l * NE, asrc, adst, hbA,
                                                     cb + l * 64, B16);
    }

    // ---- pool + head ----
    k_pool<<<NG, 256, 0, stream>>>(B16, batch, g);

    k_bn_part<64><<<2, 256, 0, stream>>>(g, NG, part);
    k_bn_adj<<<1, 64, 0, stream>>>(part, 2, NG, 64, lW, lb, 64, sc2, badj2);
    k_gemm_head<<<(NG + 31) / 32, 256, 0, stream>>>(g, lW, sc2, badj2, y, NG);

    k_bn_part<64><<<2, 256, 0, stream>>>(y, NG, part);
    k_bn_adj<<<1, 64, 0, stream>>>(part, 2, NG, 64, clW, clb, 10, sc3, badj3);
    k_cls<<<NG, 64, 0, stream>>>(y, clW, sc3, badj3, out);
}

// Round 12
// 674.735 us; speedup vs baseline: 1.0397x; 1.0213x over previous
//
#include <hip/hip_runtime.h>
#include <math.h>

#define NN 100000
#define NE 1600000
#define NG 512
#define NCLS 10
#define NEG 0.2f
#define BNEPS 1e-5f
#define BNB 1e-4f
#define MNEG -1e30f

#define NBUK 391      // buckets of 256 nodes
#define CHUNK2 4096   // edges per partition block (39KB LDS -> 4 blocks/CU)
#define NB2 391       // ceil(NE/CHUNK2)
#define CAP3 5120     // per-bucket LDS capacity

typedef unsigned short u16;
typedef unsigned int u32;
typedef _Float16 f16;
typedef __attribute__((ext_vector_type(2))) f16 f16x2;
typedef __attribute__((ext_vector_type(8))) f16 f16x8;
typedef __attribute__((ext_vector_type(4))) float f32x4;

__device__ __forceinline__ float lrelu(float v) { return v > 0.f ? v : NEG * v; }
__device__ __forceinline__ u16 f2h(float x) { union { u16 s; f16 h; } c; c.h = (f16)x; return c.s; }
__device__ __forceinline__ float h2f(u16 s) { union { u16 s; f16 h; } c; c.s = s; return (float)c.h; }
__device__ __forceinline__ f16x2 u2h2(u32 u) { union { u32 u; f16x2 h; } c; c.u = u; return c.h; }
__device__ __forceinline__ u32 packp(float p) { u32 h = f2h(p); return h | (h << 16); }

// ---------------- BatchNorm stats (f32 input) ----------------
template<int C>
__global__ __launch_bounds__(256) void k_bn_part(const float* __restrict__ x, int rows,
                                                 float* __restrict__ part) {
    const int RPI = 256 / C;
    int col = threadIdx.x % C;
    int sub = threadIdx.x / C;
    int nb = gridDim.x;
    int rpb = (rows + nb - 1) / nb;
    int r0 = blockIdx.x * rpb;
    int r1 = min(rows, r0 + rpb);
    float s = 0.f, q = 0.f;
    for (int r = r0 + sub; r < r1; r += RPI) {
        float v = x[(size_t)r * C + col];
        s += v; q += v * v;
    }
    __shared__ float ls[256], lq[256];
    ls[threadIdx.x] = s; lq[threadIdx.x] = q;
    __syncthreads();
    for (int st = RPI / 2; st > 0; st >>= 1) {
        if (sub < st) {
            ls[threadIdx.x] += ls[threadIdx.x + st * C];
            lq[threadIdx.x] += lq[threadIdx.x + st * C];
        }
        __syncthreads();
    }
    if (sub == 0) {
        part[(size_t)blockIdx.x * C + col] = ls[col];
        part[(size_t)(nb + blockIdx.x) * C + col] = lq[col];
    }
}

// f16-input variant, C=64
__global__ __launch_bounds__(256) void k_bn_part16(const u16* __restrict__ x, int rows,
                                                   float* __restrict__ part) {
    int col = threadIdx.x & 63;
    int sub = threadIdx.x >> 6;
    int nb = gridDim.x;
    int rpb = (rows + nb - 1) / nb;
    int r0 = blockIdx.x * rpb;
    int r1 = min(rows, r0 + rpb);
    float s = 0.f, q = 0.f;
    for (int r = r0 + sub; r < r1; r += 4) {
        float v = h2f(x[(size_t)r * 64 + col]);
        s += v; q += v * v;
    }
    __shared__ float ls[256], lq[256];
    ls[threadIdx.x] = s; lq[threadIdx.x] = q;
    __syncthreads();
    for (int st = 2; st > 0; st >>= 1) {
        if (sub < st) {
            ls[threadIdx.x] += ls[threadIdx.x + st * 64];
            lq[threadIdx.x] += lq[threadIdx.x + st * 64];
        }
        __syncthreads();
    }
    if (sub == 0) {
        part[(size_t)blockIdx.x * 64 + col] = ls[col];
        part[(size_t)(nb + blockIdx.x) * 64 + col] = lq[col];
    }
}

// small bn_adj (head path)
__global__ __launch_bounds__(64) void k_bn_adj(const float* __restrict__ part, int nb, int rows, int C,
                                               const float* __restrict__ W, const float* __restrict__ b,
                                               int Ncol, float* __restrict__ sc, float* __restrict__ badj) {
    int c = threadIdx.x;
    __shared__ float shl[64];
    if (c < C) {
        float s = 0.f, q = 0.f;
        for (int bb = 0; bb < nb; bb++) {
            s += part[(size_t)bb * C + c];
            q += part[(size_t)(nb + bb) * C + c];
        }
        float mu = s / rows;
        float var = q / rows - mu * mu;
        float sl = rsqrtf(var + BNEPS);
        sc[c] = sl;
        shl[c] = BNB - mu * sl;
    }
    __syncthreads();
    if (c < Ncol) {
        float a = b ? b[c] : 0.f;
        for (int k = 0; k < C; k++) a += shl[k] * W[(size_t)k * Ncol + c];
        badj[c] = a;
    }
}

// fused: BN stats + badj + f16 MFMA B-fragments (sc folded into W)
template<int C>
__global__ __launch_bounds__(256) void k_bnadjf(const float* __restrict__ part, int nb, int rows,
                                                const float* __restrict__ W, const float* __restrict__ b,
                                                float* __restrict__ badj, u16* __restrict__ Bff) {
    int t = threadIdx.x;
    int c = t & 63, seg = t >> 6;
    __shared__ float rs[4][64], rq[4][64];
    __shared__ float scl[64], shl[64];
    float s = 0.f, q = 0.f;
    if (c < C)
        for (int bb = seg; bb < nb; bb += 4) {
            s += part[(size_t)bb * C + c];
            q += part[(size_t)(nb + bb) * C + c];
        }
    rs[seg][c] = s; rq[seg][c] = q;
    __syncthreads();
    if (t < C) {
        float ss = rs[0][t] + rs[1][t] + rs[2][t] + rs[3][t];
        float qq = rq[0][t] + rq[1][t] + rq[2][t] + rq[3][t];
        float mu = ss / rows;
        float var = qq / rows - mu * mu;
        float sl = rsqrtf(var + BNEPS);
        scl[t] = sl; shl[t] = BNB - mu * sl;
    }
    __syncthreads();
    float a = 0.f;
    for (int k = seg; k < C; k += 4) a += shl[k] * W[(size_t)k * 64 + c];
    rs[seg][c] = a;
    __syncthreads();
    if (t < 64) badj[t] = (b ? b[t] : 0.f) + rs[0][t] + rs[1][t] + rs[2][t] + rs[3][t];
    const int KB = C / 32;
    for (int idx = t; idx < 4 * KB * 64 * 8; idx += 256) {
        int j = idx & 7;
        int lane = (idx >> 3) & 63;
        int kb = (idx >> 9) % KB;
        int ct = idx / (KB * 512);
        int k = kb * 32 + (lane >> 4) * 8 + j;
        int col = ct * 16 + (lane & 15);
        Bff[idx] = f2h(scl[k] * W[(size_t)k * 64 + col]);
    }
}

// ---------------- MFMA node GEMM ----------------
template<int KB, int EPI, bool F32IN>
__global__ __launch_bounds__(256) void k_gemm_mf(const void* __restrict__ xin,
                                                 const u16* __restrict__ Bff,
                                                 const float* __restrict__ badj,
                                                 u16* __restrict__ outb, int rows,
                                                 const float* __restrict__ att, float* __restrict__ hs,
                                                 const float* __restrict__ as_, const float* __restrict__ ad_,
                                                 float* __restrict__ asrc, float* __restrict__ adst) {
    int wid = threadIdx.x >> 6, lane = threadIdx.x & 63;
    int er = lane & 15, kh = lane >> 4;
    int r0 = blockIdx.x * 64;
    int rw = r0 + wid * 16;
    __shared__ u16 Dl[64][68];
    f16x8 bf[4][KB];
#pragma unroll
    for (int ct = 0; ct < 4; ct++)
#pragma unroll
        for (int kb = 0; kb < KB; kb++)
            bf[ct][kb] = *(const f16x8*)(Bff + ((size_t)(ct * KB + kb) * 64 + lane) * 8);
    f16x8 af[KB];
    int arow = rw + er;
    if (F32IN) {
        const float* xf = (const float*)xin;
        f16x8 av = (f16x8)(f16)0.f;
        if (arow < rows) {
            const float4* p = (const float4*)(xf + (size_t)arow * 32 + kh * 8);
            float4 v0 = p[0], v1 = p[1];
            av[0] = (f16)v0.x; av[1] = (f16)v0.y; av[2] = (f16)v0.z; av[3] = (f16)v0.w;
            av[4] = (f16)v1.x; av[5] = (f16)v1.y; av[6] = (f16)v1.z; av[7] = (f16)v1.w;
        }
        af[0] = av;
    } else {
        const u16* xh = (const u16*)xin;
#pragma unroll
        for (int kb = 0; kb < KB; kb++) {
            f16x8 av = (f16x8)(f16)0.f;
            if (arow < rows) av = *(const f16x8*)(xh + (size_t)arow * 64 + kb * 32 + kh * 8);
            af[kb] = av;
        }
    }
    f32x4 d[4];
#pragma unroll
    for (int ct = 0; ct < 4; ct++) {
        float bj = badj[ct * 16 + er];
        f32x4 cc = {bj, bj, bj, bj};
#pragma unroll
        for (int kb = 0; kb < KB; kb++)
            cc = __builtin_amdgcn_mfma_f32_16x16x32_f16(af[kb], bf[ct][kb], cc, 0, 0, 0);
        d[ct] = cc;
    }
#pragma unroll
    for (int ct = 0; ct < 4; ct++)
#pragma unroll
        for (int r = 0; r < 4; r++)
            Dl[wid * 16 + kh * 4 + r][ct * 16 + er] = f2h(d[ct][r]);
    if (EPI == 1) {
        float av[4];
#pragma unroll
        for (int ct = 0; ct < 4; ct++) av[ct] = att[ct * 16 + er];
#pragma unroll
        for (int r = 0; r < 4; r++) {
            float v = d[0][r] * av[0] + d[1][r] * av[1] + d[2][r] * av[2] + d[3][r] * av[3];
#pragma unroll
            for (int o = 1; o < 16; o <<= 1) v += __shfl_xor(v, o);
            int rr = rw + kh * 4 + r;
            if (er == 0 && rr < rows) hs[rr] = v;
        }
    }
    if (EPI == 2) {
        float a1v[4], a2v[4];
#pragma unroll
        for (int ct = 0; ct < 4; ct++) { a1v[ct] = as_[ct * 16 + er]; a2v[ct] = ad_[ct * 16 + er]; }
#pragma unroll
        for (int ct = 0; ct < 4; ct++) {
#pragma unroll
            for (int r = 0; r < 4; r++) {
                float s1 = d[ct][r] * a1v[ct], s2 = d[ct][r] * a2v[ct];
#pragma unroll
                for (int o = 1; o < 16; o <<= 1) { s1 += __shfl_xor(s1, o); s2 += __shfl_xor(s2, o); }
                int rr = rw + kh * 4 + r;
                if (er == 0 && rr < rows) {
                    asrc[(size_t)rr * 4 + ct] = s1;
                    adst[(size_t)rr * 4 + ct] = s2;
                }
            }
        }
    }
    __syncthreads();
    const u32* D32 = (const u32*)&Dl[0][0];
    u32* out32 = (u32*)outb;
    for (int idx = threadIdx.x; idx < 64 * 32; idx += 256) {
        int r = idx >> 5, c2 = idx & 31;
        int rr = r0 + r;
        if (rr < rows) out32[(size_t)rr * 32 + c2] = D32[r * 34 + c2];
    }
}

// ---------------- head GEMM (f32, small) ----------------
__global__ __launch_bounds__(256) void k_gemm_head(const float* __restrict__ x, const float* __restrict__ W,
                                                   const float* __restrict__ sc, const float* __restrict__ badj,
                                                   float* __restrict__ outf, int rows) {
    __shared__ float Ws[64 * 64];
    __shared__ float Xs[32 * 64];
    int r0 = blockIdx.x * 32;
    for (int i = threadIdx.x; i < 64 * 64; i += 256) Ws[i] = W[i];
    for (int i = threadIdx.x; i < 32 * 64; i += 256) {
        int r = i / 64, k = i % 64;
        int rr = r0 + r;
        Xs[i] = (rr < rows) ? x[(size_t)rr * 64 + k] * sc[k] : 0.f;
    }
    __syncthreads();
    int col = threadIdx.x & 63;
    int rg = threadIdx.x >> 6;
    float b0 = badj[col];
    float acc[8];
#pragma unroll
    for (int i = 0; i < 8; i++) acc[i] = b0;
    for (int k = 0; k < 64; k++) {
        float w = Ws[k * 64 + col];
#pragma unroll
        for (int i = 0; i < 8; i++) acc[i] += Xs[(rg * 8 + i) * 64 + k] * w;
    }
#pragma unroll
    for (int i = 0; i < 8; i++) {
        int r = r0 + rg * 8 + i;
        if (r < rows) outf[(size_t)r * 64 + col] = fmaxf(acc[i], 0.f);
    }
}

// folded attention weights + edgepre MFMA B-fragments
__global__ __launch_bounds__(768) void k_we(const float* __restrict__ cWe, const float* __restrict__ cae,
                                            const float* __restrict__ Wee, const float* __restrict__ att,
                                            const float* __restrict__ bee, float* __restrict__ wEbuf,
                                            u16* __restrict__ Bf1, u16* __restrict__ Bf2) {
    int t = threadIdx.x;
    int l = t >> 8;
    int h = (t >> 6) & 3;
    int k = t & 63;
    float a = 0.f;
    for (int d = 0; d < 16; d++)
        a += cWe[(size_t)l * 4096 + k * 64 + h * 16 + d] * cae[l * 64 + h * 16 + d];
    wEbuf[t] = a;
    if (t < 16) {
        float v = 0.f;
        for (int j = 0; j < 64; j++) v += Wee[t * 64 + j] * att[j];
        wEbuf[768 + t] = v;
    }
    if (t == 16) {
        float v = 0.f;
        for (int j = 0; j < 64; j++) v += bee[j] * att[j];
        wEbuf[784] = v;
    }
    for (int idx = t; idx < 4 * 64 * 8; idx += 768) {
        int cb = idx >> 9, ln = (idx >> 3) & 63, j = idx & 7;
        int col = cb * 16 + (ln & 15);
        int kk = (ln >> 4) * 8 + j;
        float v = (kk < 16) ? Wee[kk * 64 + col] : 0.f;
        Bf1[idx] = f2h(v);
    }
    __syncthreads();
    for (int idx = t; idx < 2 * 64 * 8; idx += 768) {
        int kb = idx >> 9, ln = (idx >> 3) & 63, j = idx & 7;
        int n = ln & 15;
        int kk = kb * 32 + (ln >> 4) * 8 + j;
        float v = (n < 12) ? wEbuf[n * 64 + kk] : 0.f;
        Bf2[idx] = f2h(v);
    }
}

// ---------------- CSR build via LDS counting sort ----------------
__global__ __launch_bounds__(256) void k_bhist(const int* __restrict__ dst, int* __restrict__ hist) {
    __shared__ int lh[512];
    int t = threadIdx.x;
    lh[t] = 0; lh[t + 256] = 0;
    __syncthreads();
    int base = blockIdx.x * CHUNK2;
    int cnt = min(CHUNK2, NE - base);
    for (int i = t; i < cnt; i += 256) atomicAdd(&lh[dst[base + i] >> 8], 1);
    __syncthreads();
    for (int b = t; b < NBUK; b += 256) hist[blockIdx.x * NBUK + b] = lh[b];
}

__global__ __launch_bounds__(256) void k_colsum(const int* __restrict__ hist, int* __restrict__ colsum) {
    int col = blockIdx.x;
    int t = threadIdx.x;
    int s = 0;
    for (int b = t; b < NB2; b += 256) s += hist[b * NBUK + col];
    __shared__ int ls[256];
    ls[t] = s;
    __syncthreads();
    for (int st = 128; st; st >>= 1) {
        if (t < st) ls[t] += ls[t + st];
        __syncthreads();
    }
    if (t == 0) colsum[col] = ls[0];
}

__global__ __launch_bounds__(512) void k_bukscan(const int* __restrict__ colsum,
                                                 int* __restrict__ bucketBase, int* __restrict__ rowp) {
    __shared__ int ls[512];
    int t = threadIdx.x;
    int v = (t < NBUK) ? colsum[t] : 0;
    ls[t] = v;
    __syncthreads();
    for (int off = 1; off < 512; off <<= 1) {
        int a = (t >= off) ? ls[t - off] : 0;
        __syncthreads();
        ls[t] += a;
        __syncthreads();
    }
    if (t < NBUK) bucketBase[t] = ls[t] - v;
    if (t == 0) { bucketBase[NBUK] = NE; rowp[NN] = NE; }
}

__global__ __launch_bounds__(512) void k_coloffs(const int* __restrict__ hist,
                                                 const int* __restrict__ bucketBase, int* __restrict__ offs) {
    int col = blockIdx.x;
    int t = threadIdx.x;
    __shared__ int ls[512];
    int v = (t < NB2) ? hist[(size_t)t * NBUK + col] : 0;
    ls[t] = v;
    __syncthreads();
    for (int off = 1; off < 512; off <<= 1) {
        int a = (t >= off) ? ls[t - off] : 0;
        __syncthreads();
        ls[t] += a;
        __syncthreads();
    }
    if (t < NB2) offs[(size_t)t * NBUK + col] = bucketBase[col] + ls[t] - v;
}

__global__ __launch_bounds__(256) void k_part(const int* __restrict__ src, const int* __restrict__ dst,
                                              const int* __restrict__ offs, int2* __restrict__ seTmp) {
    __shared__ int lhist[512];
    __shared__ int lstart[NBUK + 1];
    __shared__ int lcur[NBUK];
    __shared__ int loffs[NBUK];
    __shared__ int2 stage[CHUNK2];
    int t = threadIdx.x;
    int base = blockIdx.x * CHUNK2;
    int cnt = min(CHUNK2, NE - base);
    int blkrow = blockIdx.x * NBUK;
    lhist[t] = 0; lhist[t + 256] = 0;
    __syncthreads();
    for (int i = t; i < cnt; i += 256) atomicAdd(&lhist[dst[base + i] >> 8], 1);
    __syncthreads();
    for (int off = 1; off < 512; off <<= 1) {
        int v0 = (t >= off) ? lhist[t - off] : 0;
        int v1 = lhist[t + 256 - off];
        __syncthreads();
        lhist[t] += v0; lhist[t + 256] += v1;
        __syncthreads();
    }
    if (t == 0) lstart[0] = 0;
    lstart[t + 1] = lhist[t];
    if (t + 257 <= NBUK) lstart[t + 257] = lhist[t + 256];
    __syncthreads();
    for (int b = t; b < NBUK; b += 256) {
        lcur[b] = lstart[b];
        loffs[b] = offs[blkrow + b];
    }
    __syncthreads();
    for (int i = t; i < cnt; i += 256) {
        int e = base + i;
        int d = dst[e];
        int b = d >> 8;
        int pos = atomicAdd(&lcur[b], 1);
        int2 v; v.x = src[e] | (b << 17); v.y = e | ((d & 255) << 21);
        stage[pos] = v;
    }
    __syncthreads();
    for (int q = t; q < cnt; q += 256) {
        int2 v = stage[q];
        int b = ((u32)v.x) >> 17;
        int2 o; o.x = v.x & 0x1FFFF; o.y = v.y;
        seTmp[loffs[b] + (q - lstart[b])] = o;
    }
}

// per-bucket fine sort; outputs srcS[] and eord[] separately + rowp
__global__ __launch_bounds__(256) void k_bucket(const int2* __restrict__ seTmp,
                                                const int* __restrict__ bucketBase,
                                                int* __restrict__ srcS, int* __restrict__ eord,
                                                int* __restrict__ rowp) {
    int b = blockIdx.x;
    int t = threadIdx.x;
    int beg = bucketBase[b], end = bucketBase[b + 1];
    int cnt = end - beg;
    __shared__ int lhist[256], lscan[256], lcur[256];
    __shared__ int2 ebuf[CAP3];
    lhist[t] = 0;
    __syncthreads();
    for (int i = t; i < cnt; i += 256)
        atomicAdd(&lhist[((u32)seTmp[beg + i].y) >> 21], 1);
    __syncthreads();
    lscan[t] = lhist[t];
    __syncthreads();
    for (int off = 1; off < 256; off <<= 1) {
        int v = (t >= off) ? lscan[t - off] : 0;
        __syncthreads();
        lscan[t] += v;
        __syncthreads();
    }
    int excl = lscan[t] - lhist[t];
    lcur[t] = excl;
    int node = b * 256 + t;
    if (node < NN) rowp[node] = beg + excl;
    __syncthreads();
    if (cnt <= CAP3) {
        for (int i = t; i < cnt; i += 256) {
            int2 v = seTmp[beg + i];
            int dl = ((u32)v.y) >> 21;
            int pos = atomicAdd(&lcur[dl], 1);
            int2 o; o.x = v.x; o.y = v.y & 0x1FFFFF;
            ebuf[pos] = o;
        }
        __syncthreads();
        for (int q = t; q < cnt; q += 256) {
            srcS[beg + q] = ebuf[q].x;
            eord[beg + q] = ebuf[q].y;
        }
    } else {
        for (int i = t; i < cnt; i += 256) {
            int2 v = seTmp[beg + i];
            int dl = ((u32)v.y) >> 21;
            int pos = atomicAdd(&lcur[dl], 1);
            srcS[beg + pos] = v.x;
            eord[beg + pos] = v.y & 0x1FFFFF;
        }
    }
}

// ---------------- edge precompute via MFMA: 32 edges/wave ----------------
__global__ __launch_bounds__(256) void k_edgepre(const float* __restrict__ ea,
                                                 const u16* __restrict__ Bf1, const u16* __restrict__ Bf2,
                                                 const float* __restrict__ bee, const float* __restrict__ wEbuf,
                                                 const int* __restrict__ eord,
                                                 float* __restrict__ heatt, ushort4* __restrict__ aedH) {
    int wid = threadIdx.x >> 6, lane = threadIdx.x & 63;
    int p0 = (blockIdx.x * 4 + wid) * 32;
    __shared__ f16 EaD[4][32][24];
    __shared__ f16 Pl[4][32][72];
    f16x8 bf1[4], bf2[2];
#pragma unroll
    for (int cb = 0; cb < 4; cb++) bf1[cb] = *(const f16x8*)(Bf1 + ((size_t)cb * 64 + lane) * 8);
#pragma unroll
    for (int kb = 0; kb < 2; kb++) bf2[kb] = *(const f16x8*)(Bf2 + ((size_t)kb * 64 + lane) * 8);
    int e = lane & 31, q = lane >> 5;
    int ei = eord[p0 + e];
    const float4* pa = (const float4*)(ea + (size_t)ei * 16 + q * 8);
    float4 v0 = pa[0], v1 = pa[1];
    {
        const float* va = wEbuf + 768 + q * 8;
        float part = v0.x * va[0] + v0.y * va[1] + v0.z * va[2] + v0.w * va[3]
                   + v1.x * va[4] + v1.y * va[5] + v1.z * va[6] + v1.w * va[7];
        float po = __shfl_xor(part, 32);
        if (lane < 32) heatt[p0 + e] = part + po + wEbuf[784];
    }
    {
        f16x8 t;
        t[0] = (f16)v0.x; t[1] = (f16)v0.y; t[2] = (f16)v0.z; t[3] = (f16)v0.w;
        t[4] = (f16)v1.x; t[5] = (f16)v1.y; t[6] = (f16)v1.z; t[7] = (f16)v1.w;
        *(f16x8*)&EaD[wid][e][q * 8] = t;
    }
    __builtin_amdgcn_wave_barrier();
    int er = lane & 15, kh = lane >> 4;
    f16x8 a0f = (f16x8)(f16)0.f, a1f = (f16x8)(f16)0.f;
    if (kh < 2) {
        a0f = *(const f16x8*)&EaD[wid][er][kh * 8];
        a1f = *(const f16x8*)&EaD[wid][16 + er][kh * 8];
    }
    f32x4 z = {0.f, 0.f, 0.f, 0.f};
    f32x4 d0[4], d1[4];
#pragma unroll
    for (int ct = 0; ct < 4; ct++) {
        d0[ct] = __builtin_amdgcn_mfma_f32_16x16x32_f16(a0f, bf1[ct], z, 0, 0, 0);
        d1[ct] = __builtin_amdgcn_mfma_f32_16x16x32_f16(a1f, bf1[ct], z, 0, 0, 0);
    }
    {
#pragma unroll
        for (int ct = 0; ct < 4; ct++) {
            float bb = bee[ct * 16 + er];
#pragma unroll
            for (int r = 0; r < 4; r++) {
                Pl[wid][kh * 4 + r][ct * 16 + er] = (f16)fmaxf(d0[ct][r] + bb, 0.f);
                Pl[wid][16 + kh * 4 + r][ct * 16 + er] = (f16)fmaxf(d1[ct][r] + bb, 0.f);
            }
        }
    }
    __builtin_amdgcn_wave_barrier();
    f16x8 pa00 = *(const f16x8*)&Pl[wid][er][kh * 8];
    f16x8 pa01 = *(const f16x8*)&Pl[wid][er][32 + kh * 8];
    f16x8 pa10 = *(const f16x8*)&Pl[wid][16 + er][kh * 8];
    f16x8 pa11 = *(const f16x8*)&Pl[wid][16 + er][32 + kh * 8];
    f32x4 dd0 = __builtin_amdgcn_mfma_f32_16x16x32_f16(pa00, bf2[0], z, 0, 0, 0);
    dd0 = __builtin_amdgcn_mfma_f32_16x16x32_f16(pa01, bf2[1], dd0, 0, 0, 0);
    f32x4 dd1 = __builtin_amdgcn_mfma_f32_16x16x32_f16(pa10, bf2[0], z, 0, 0, 0);
    dd1 = __builtin_amdgcn_mfma_f32_16x16x32_f16(pa11, bf2[1], dd1, 0, 0, 0);
    __builtin_amdgcn_wave_barrier();
#pragma unroll
    for (int r = 0; r < 4; r++) {
        EaD[wid][kh * 4 + r][er] = (f16)dd0[r];
        EaD[wid][16 + kh * 4 + r][er] = (f16)dd1[r];
    }
    __builtin_amdgcn_wave_barrier();
    {
        int e2 = lane & 31, l3 = lane >> 5;
        ushort4 o = *(const ushort4*)&EaD[wid][e2][l3 * 4];
        aedH[(size_t)l3 * NE + p0 + e2] = o;
        if (lane < 32) {
            ushort4 o2 = *(const ushort4*)&EaD[wid][lane][8];
            aedH[(size_t)2 * NE + p0 + lane] = o2;
        }
    }
}

// ---------------- EGAT aggregation: 4 cols/lane, packed f16 gather ----------------
__global__ __launch_bounds__(256) void k_egat_agg(const int* __restrict__ rowp, const int* __restrict__ srcS,
                                                  const float* __restrict__ heatt, const float* __restrict__ hs,
                                                  const u16* __restrict__ hb, u16* __restrict__ xout) {
    int wid = threadIdx.x >> 6, lane = threadIdx.x & 63;
    int n = blockIdx.x * 4 + wid;
    if (n >= NN) return;
    int beg = rowp[n], deg = rowp[n + 1] - beg;
    if (deg == 0) { xout[(size_t)n * 64 + lane] = 0; return; }
    float hsn = hs[n];
    __shared__ u32 plp[4][64];
    __shared__ int soff[4][64];
    if (deg <= 64) {
        int s = 0; float lg = MNEG;
        if (lane < deg) {
            s = srcS[beg + lane];
            lg = lrelu(hs[s] + hsn + heatt[beg + lane]);
        }
        float m = lg;
#pragma unroll
        for (int o = 32; o; o >>= 1) m = fmaxf(m, __shfl_xor(m, o));
        float e = (lane < deg) ? __expf(lg - m) : 0.f;
        float sm = e;
#pragma unroll
        for (int o = 32; o; o >>= 1) sm += __shfl_xor(sm, o);
        float p = e * (1.f / sm);
        plp[wid][lane] = packp(p);
        soff[wid][lane] = s << 7;
        __builtin_amdgcn_wave_barrier();
        int cq = lane & 15, q = lane >> 4;
        const u32* prow = &plp[wid][0];
        const int* srow = &soff[wid][0];
        const char* hp = (const char*)hb + cq * 8;
        f16x2 a01a = (f16x2)(f16)0.f, a23a = (f16x2)(f16)0.f;
        f16x2 a01b = (f16x2)(f16)0.f, a23b = (f16x2)(f16)0.f;
        for (int j = 0; j < deg; j += 8) {
            int e0 = j + q, e1 = j + 4 + q;
            u32 pp0 = prow[e0]; int o0 = srow[e0];
            u32 pp1 = prow[e1]; int o1 = srow[e1];
            uint2 w0 = *(const uint2*)(hp + o0);
            uint2 w1 = *(const uint2*)(hp + o1);
            f16x2 q0 = u2h2(pp0), q1 = u2h2(pp1);
            a01a = q0 * u2h2(w0.x) + a01a;
            a23a = q0 * u2h2(w0.y) + a23a;
            a01b = q1 * u2h2(w1.x) + a01b;
            a23b = q1 * u2h2(w1.y) + a23b;
        }
        float c0 = (float)a01a[0] + (float)a01b[0];
        float c1 = (float)a01a[1] + (float)a01b[1];
        float c2 = (float)a23a[0] + (float)a23b[0];
        float c3 = (float)a23a[1] + (float)a23b[1];
        c0 += __shfl_xor(c0, 16); c0 += __shfl_xor(c0, 32);
        c1 += __shfl_xor(c1, 16); c1 += __shfl_xor(c1, 32);
        c2 += __shfl_xor(c2, 16); c2 += __shfl_xor(c2, 32);
        c3 += __shfl_xor(c3, 16); c3 += __shfl_xor(c3, 32);
        if (lane < 16) {
            ushort4 o;
            o.x = f2h(fmaxf(c0, 0.f));
            o.y = f2h(fmaxf(c1, 0.f));
            o.z = f2h(fmaxf(c2, 0.f));
            o.w = f2h(fmaxf(c3, 0.f));
            *(ushort4*)(xout + (size_t)n * 64 + cq * 4) = o;
        }
    } else {
        float m = MNEG, sm = 0.f;
        for (int i = lane; i < deg; i += 64) {
            float v = lrelu(hs[srcS[beg + i]] + hsn + heatt[beg + i]);
            float mn = fmaxf(m, v);
            sm = sm * __expf(m - mn) + __expf(v - mn);
            m = mn;
        }
#pragma unroll
        for (int o = 32; o; o >>= 1) {
            float mo = __shfl_xor(m, o), so = __shfl_xor(sm, o);
            float mn = fmaxf(m, mo);
            sm = sm * __expf(m - mn) + so * __expf(mo - mn);
            m = mn;
        }
        float inv = 1.f / sm;
        float acc0 = 0.f;
        for (int base = 0; base < deg; base += 64) {
            int i = base + lane;
            int s = 0; float p = 0.f;
            if (i < deg) {
                s = srcS[beg + i];
                p = __expf(lrelu(hs[s] + hsn + heatt[beg + i]) - m) * inv;
            }
            int mm = min(64, deg - base);
            for (int j = 0; j < mm; j++) {
                int s0 = __shfl(s, j); float q0 = __shfl(p, j);
                acc0 = fmaf(q0, h2f(hb[(size_t)s0 * 64 + lane]), acc0);
            }
        }
        xout[(size_t)n * 64 + lane] = f2h(fmaxf(acc0, 0.f));
    }
}

// ---------------- conv aggregation: e-major stride-5 plp (conflict-free) ----------------
__global__ __launch_bounds__(256) void k_conv_agg(const int* __restrict__ rowp, const int* __restrict__ srcS,
                                                  const ushort4* __restrict__ aedH, const float* __restrict__ asrc,
                                                  const float* __restrict__ adst, const u16* __restrict__ hb,
                                                  const float* __restrict__ bias, u16* __restrict__ xout) {
    int wid = threadIdx.x >> 6, lane = threadIdx.x & 63;
    int n = blockIdx.x * 4 + wid;
    if (n >= NN) return;
    int beg = rowp[n], deg = rowp[n + 1] - beg;
    if (deg == 0) { xout[(size_t)n * 64 + lane] = f2h(fmaxf(bias[lane], 0.f)); return; }
    float4 an = ((const float4*)adst)[n];
    // e-major stride-5: read addr = 5*(j+q)+h, banks 5q+h all-distinct over (q,h) in [0,4)^2
    __shared__ u32 plp[4][64][5];
    __shared__ int soff[4][64];
    __shared__ float plsF[4][4][72];
    __shared__ int slF[4][64];
    if (deg <= 64) {
        int s = 0;
        float l0 = MNEG, l1 = MNEG, l2 = MNEG, l3 = MNEG;
        if (lane < deg) {
            s = srcS[beg + lane];
            float4 as4 = ((const float4*)asrc)[s];
            ushort4 u = aedH[beg + lane];
            l0 = lrelu(as4.x + an.x + h2f(u.x));
            l1 = lrelu(as4.y + an.y + h2f(u.y));
            l2 = lrelu(as4.z + an.z + h2f(u.z));
            l3 = lrelu(as4.w + an.w + h2f(u.w));
        }
        float m0 = l0, m1 = l1, m2 = l2, m3 = l3;
#pragma unroll
        for (int o = 32; o; o >>= 1) {
            m0 = fmaxf(m0, __shfl_xor(m0, o)); m1 = fmaxf(m1, __shfl_xor(m1, o));
            m2 = fmaxf(m2, __shfl_xor(m2, o)); m3 = fmaxf(m3, __shfl_xor(m3, o));
        }
        float e0 = (lane < deg) ? __expf(l0 - m0) : 0.f;
        float e1 = (lane < deg) ? __expf(l1 - m1) : 0.f;
        float e2 = (lane < deg) ? __expf(l2 - m2) : 0.f;
        float e3 = (lane < deg) ? __expf(l3 - m3) : 0.f;
        float s0 = e0, s1 = e1, s2 = e2, s3 = e3;
#pragma unroll
        for (int o = 32; o; o >>= 1) {
            s0 += __shfl_xor(s0, o); s1 += __shfl_xor(s1, o);
            s2 += __shfl_xor(s2, o); s3 += __shfl_xor(s3, o);
        }
        plp[wid][lane][0] = packp(e0 * (1.f / s0));
        plp[wid][lane][1] = packp(e1 * (1.f / s1));
        plp[wid][lane][2] = packp(e2 * (1.f / s2));
        plp[wid][lane][3] = packp(e3 * (1.f / s3));
        soff[wid][lane] = s << 7;
        __builtin_amdgcn_wave_barrier();
        int cq = lane & 15, q = lane >> 4;
        int hh = cq >> 2;
        const u32* prow = &plp[wid][0][0];
        const int* srow = &soff[wid][0];
        const char* hp = (const char*)hb + cq * 8;
        f16x2 a01a = (f16x2)(f16)0.f, a23a = (f16x2)(f16)0.f;
        f16x2 a01b = (f16x2)(f16)0.f, a23b = (f16x2)(f16)0.f;
        for (int j = 0; j < deg; j += 8) {
            int e0i = j + q, e1i = j + 4 + q;
            u32 pp0 = prow[e0i * 5 + hh]; int o0 = srow[e0i];
            u32 pp1 = prow[e1i * 5 + hh]; int o1 = srow[e1i];
            uint2 w0 = *(const uint2*)(hp + o0);
            uint2 w1 = *(const uint2*)(hp + o1);
            f16x2 q0 = u2h2(pp0), q1 = u2h2(pp1);
            a01a = q0 * u2h2(w0.x) + a01a;
            a23a = q0 * u2h2(w0.y) + a23a;
            a01b = q1 * u2h2(w1.x) + a01b;
            a23b = q1 * u2h2(w1.y) + a23b;
        }
        float c0 = (float)a01a[0] + (float)a01b[0];
        float c1 = (float)a01a[1] + (float)a01b[1];
        float c2 = (float)a23a[0] + (float)a23b[0];
        float c3 = (float)a23a[1] + (float)a23b[1];
        c0 += __shfl_xor(c0, 16); c0 += __shfl_xor(c0, 32);
        c1 += __shfl_xor(c1, 16); c1 += __shfl_xor(c1, 32);
        c2 += __shfl_xor(c2, 16); c2 += __shfl_xor(c2, 32);
        c3 += __shfl_xor(c3, 16); c3 += __shfl_xor(c3, 32);
        if (lane < 16) {
            ushort4 o;
            o.x = f2h(fmaxf(c0 + bias[cq * 4 + 0], 0.f));
            o.y = f2h(fmaxf(c1 + bias[cq * 4 + 1], 0.f));
            o.z = f2h(fmaxf(c2 + bias[cq * 4 + 2], 0.f));
            o.w = f2h(fmaxf(c3 + bias[cq * 4 + 3], 0.f));
            *(ushort4*)(xout + (size_t)n * 64 + cq * 4) = o;
        }
    } else {
        int hq = lane >> 4;
        float m0 = MNEG, m1 = MNEG, m2 = MNEG, m3 = MNEG;
        float s0 = 0.f, s1 = 0.f, s2 = 0.f, s3 = 0.f;
        for (int i = lane; i < deg; i += 64) {
            int s = srcS[beg + i];
            float4 as4 = ((const float4*)asrc)[s];
            ushort4 u = aedH[beg + i];
            float l0 = lrelu(as4.x + an.x + h2f(u.x));
            float l1 = lrelu(as4.y + an.y + h2f(u.y));
            float l2 = lrelu(as4.z + an.z + h2f(u.z));
            float l3 = lrelu(as4.w + an.w + h2f(u.w));
            float n0 = fmaxf(m0, l0); s0 = s0 * __expf(m0 - n0) + __expf(l0 - n0); m0 = n0;
            float n1 = fmaxf(m1, l1); s1 = s1 * __expf(m1 - n1) + __expf(l1 - n1); m1 = n1;
            float n2 = fmaxf(m2, l2); s2 = s2 * __expf(m2 - n2) + __expf(l2 - n2); m2 = n2;
            float n3 = fmaxf(m3, l3); s3 = s3 * __expf(m3 - n3) + __expf(l3 - n3); m3 = n3;
        }
#pragma unroll
        for (int o = 32; o; o >>= 1) {
            float mo, so, mn;
            mo = __shfl_xor(m0, o); so = __shfl_xor(s0, o); mn = fmaxf(m0, mo);
            s0 = s0 * __expf(m0 - mn) + so * __expf(mo - mn); m0 = mn;
            mo = __shfl_xor(m1, o); so = __shfl_xor(s1, o); mn = fmaxf(m1, mo);
            s1 = s1 * __expf(m1 - mn) + so * __expf(mo - mn); m1 = mn;
            mo = __shfl_xor(m2, o); so = __shfl_xor(s2, o); mn = fmaxf(m2, mo);
            s2 = s2 * __expf(m2 - mn) + so * __expf(mo - mn); m2 = mn;
            mo = __shfl_xor(m3, o); so = __shfl_xor(s3, o); mn = fmaxf(m3, mo);
            s3 = s3 * __expf(m3 - mn) + so * __expf(mo - mn); m3 = mn;
        }
        float i0 = 1.f / s0, i1 = 1.f / s1, i2 = 1.f / s2, i3 = 1.f / s3;
        float acc0 = 0.f;
        for (int base = 0; base < deg; base += 64) {
            int i = base + lane;
            if (i < deg) {
                int s = srcS[beg + i];
                float4 as4 = ((const float4*)asrc)[s];
                ushort4 u = aedH[beg + i];
                plsF[wid][0][lane] = __expf(lrelu(as4.x + an.x + h2f(u.x)) - m0) * i0;
                plsF[wid][1][lane] = __expf(lrelu(as4.y + an.y + h2f(u.y)) - m1) * i1;
                plsF[wid][2][lane] = __expf(lrelu(as4.z + an.z + h2f(u.z)) - m2) * i2;
                plsF[wid][3][lane] = __expf(lrelu(as4.w + an.w + h2f(u.w)) - m3) * i3;
                slF[wid][lane] = s;
            }
            __builtin_amdgcn_wave_barrier();
            int mm = min(64, deg - base);
            const float* prow = &plsF[wid][hq][0];
            const int* srow = &slF[wid][0];
            for (int j = 0; j < mm; j++)
                acc0 = fmaf(prow[j], h2f(hb[(size_t)srow[j] * 64 + lane]), acc0);
            __builtin_amdgcn_wave_barrier();
        }
        xout[(size_t)n * 64 + lane] = f2h(fmaxf(acc0 + bias[lane], 0.f));
    }
}

// ---------------- pool + head ----------------
__device__ __forceinline__ int lowerb(const int* a, int n, int key) {
    int lo = 0, hi = n;
    while (lo < hi) {
        int mid = (lo + hi) >> 1;
        if (a[mid] < key) lo = mid + 1; else hi = mid;
    }
    return lo;
}

__global__ __launch_bounds__(256) void k_pool(const u16* __restrict__ x, const int* __restrict__ batch,
                                              float* __restrict__ g) {
    int gr = blockIdx.x;
    int lane = threadIdx.x & 63;
    int sub = threadIdx.x >> 6;
    int beg = lowerb(batch, NN, gr);
    int end = lowerb(batch, NN, gr + 1);
    float acc = 0.f;
    for (int i = beg + sub; i < end; i += 4) acc += h2f(x[(size_t)i * 64 + lane]);
    __shared__ float ls[4][64];
    ls[sub][lane] = acc;
    __syncthreads();
    if (sub == 0)
        g[(size_t)gr * 64 + lane] = ls[0][lane] + ls[1][lane] + ls[2][lane] + ls[3][lane];
}

__global__ __launch_bounds__(64) void k_cls(const float* __restrict__ y, const float* __restrict__ W,
                                            const float* __restrict__ sc, const float* __restrict__ badj,
                                            float* __restrict__ out) {
    int r = blockIdx.x, lane = threadIdx.x;
    __shared__ float yr[64];
    yr[lane] = y[(size_t)r * 64 + lane] * sc[lane];
    __syncthreads();
    float lg = -INFINITY;
    if (lane < NCLS) {
        float a = badj[lane];
        for (int k = 0; k < 64; k++) a += yr[k] * W[k * NCLS + lane];
        lg = a;
    }
    float mx = lg;
#pragma unroll
    for (int o = 32; o; o >>= 1) mx = fmaxf(mx, __shfl_xor(mx, o));
    float e = (lane < NCLS) ? expf(lg - mx) : 0.f;
    float s = e;
#pragma unroll
    for (int o = 32; o; o >>= 1) s += __shfl_xor(s, o);
    if (lane < NCLS) out[(size_t)r * NCLS + lane] = lg - mx - logf(s);
}

extern "C" void kernel_launch(void* const* d_in, const int* in_sizes, int n_in,
                              void* d_out, int out_size, void* d_ws, size_t ws_size,
                              hipStream_t stream) {
    const float* x0  = (const float*)d_in[0];
    const float* ea  = (const float*)d_in[1];
    const int* eidx  = (const int*)d_in[2];
    const int* batch = (const int*)d_in[3];
    const float* Wx  = (const float*)d_in[4];
    const float* bx  = (const float*)d_in[5];
    const float* Wee = (const float*)d_in[6];
    const float* bee = (const float*)d_in[7];
    const float* att = (const float*)d_in[8];
    const float* cW  = (const float*)d_in[9];
    const float* cWe = (const float*)d_in[10];
    const float* cas = (const float*)d_in[11];
    const float* cad = (const float*)d_in[12];
    const float* cae = (const float*)d_in[13];
    const float* cb  = (const float*)d_in[14];
    const float* lW  = (const float*)d_in[15];
    const float* lb  = (const float*)d_in[16];
    const float* clW = (const float*)d_in[17];
    const float* clb = (const float*)d_in[18];
    float* out = (float*)d_out;

    const int* srcA = eidx;
    const int* dstA = eidx + NE;

    char* w = (char*)d_ws;
    size_t off = 0;
    auto alloc = [&](size_t bytes) -> void* {
        void* p = w + off;
        off += (bytes + 255) & ~(size_t)255;
        return p;
    };
    u16* hbA      = (u16*)alloc((size_t)NN * 64 * 2);
    u16* B16      = (u16*)alloc((size_t)NN * 64 * 2);
    float* hs     = (float*)alloc((size_t)NN * 4);
    float* asrc   = (float*)alloc((size_t)NN * 4 * 4);
    float* adst   = (float*)alloc((size_t)NN * 4 * 4);
    float* heatt  = (float*)alloc((size_t)NE * 4);
    ushort4* aedH = (ushort4*)alloc((size_t)3 * NE * 8);
    int* srcS     = (int*)alloc((size_t)NE * 4);
    int* eord     = (int*)alloc((size_t)NE * 4);
    int* rowp     = (int*)alloc((size_t)(NN + 1) * 4);
    int* hist     = (int*)alloc((size_t)NB2 * NBUK * 4);
    int* offs     = (int*)alloc((size_t)NB2 * NBUK * 4);
    int* bucketBase = (int*)alloc((size_t)(NBUK + 1) * 4);
    int* colsum   = (int*)alloc((size_t)NBUK * 4);
    float* part   = (float*)alloc((size_t)2 * 200 * 64 * 4);
    float* badj   = (float*)alloc(64 * 4);
    float* wEbuf  = (float*)alloc(800 * 4);
    u16* Bf1      = (u16*)alloc(4 * 64 * 8 * 2);
    u16* Bf2      = (u16*)alloc(2 * 64 * 8 * 2);
    u16* Bff      = (u16*)alloc(8 * 64 * 8 * 2);
    float* g      = (float*)alloc((size_t)NG * 64 * 4);
    float* y      = (float*)alloc((size_t)NG * 64 * 4);
    float* badj2  = (float*)alloc(64 * 4);
    float* badj3  = (float*)alloc(64 * 4);
    float* sc2    = (float*)alloc(64 * 4);
    float* sc3    = (float*)alloc(64 * 4);
    if (off > ws_size) return;

    int2* seTmp = (int2*)aedH;  // overlay: aedH unused until edgepre

    const int NB = 200;
    const int GEMMB = (NN + 63) / 64;

    // ---- CSR build ----
    k_bhist<<<NB2, 256, 0, stream>>>(dstA, hist);
    k_colsum<<<NBUK, 256, 0, stream>>>(hist, colsum);
    k_bukscan<<<1, 512, 0, stream>>>(colsum, bucketBase, rowp);
    k_coloffs<<<NBUK, 512, 0, stream>>>(hist, bucketBase, offs);
    k_part<<<NB2, 256, 0, stream>>>(srcA, dstA, offs, seTmp);
    k_bucket<<<NBUK, 256, 0, stream>>>(seTmp, bucketBase, srcS, eord, rowp);

    // ---- folded attention weights ----
    k_we<<<1, 768, 0, stream>>>(cWe, cae, Wee, att, bee, wEbuf, Bf1, Bf2);

    // ---- BN(x0) + EGAT node GEMM ----
    k_bn_part<32><<<NB, 256, 0, stream>>>(x0, NN, part);
    k_bnadjf<32><<<1, 256, 0, stream>>>(part, NB, NN, Wx, bx, badj, Bff);
    k_gemm_mf<1, 1, true><<<GEMMB, 256, 0, stream>>>(
        x0, Bff, badj, hbA, NN, att, hs, nullptr, nullptr, nullptr, nullptr);

    // ---- edge precompute ----
    k_edgepre<<<NE / 128, 256, 0, stream>>>(ea, Bf1, Bf2, bee, wEbuf, eord, heatt, aedH);

    // ---- EGAT aggregation ----
    k_egat_agg<<<(NN + 3) / 4, 256, 0, stream>>>(rowp, srcS, heatt, hs, hbA, B16);

    // ---- 3 GATConv layers ----
    for (int l = 0; l < 3; l++) {
        k_bn_part16<<<NB, 256, 0, stream>>>(B16, NN, part);
        k_bnadjf<64><<<1, 256, 0, stream>>>(part, NB, NN, cW + (size_t)l * 4096, nullptr, badj, Bff);
        k_gemm_mf<2, 2, false><<<GEMMB, 256, 0, stream>>>(
            B16, Bff, badj, hbA, NN, nullptr, nullptr,
            cas + l * 64, cad + l * 64, asrc, adst);
        k_conv_agg<<<(NN + 3) / 4, 256, 0, stream>>>(rowp, srcS, aedH + (size_t)l * NE, asrc, adst, hbA,
                                                     cb + l * 64, B16);
    }

    // ---- pool + head ----
    k_pool<<<NG, 256, 0, stream>>>(B16, batch, g);

    k_bn_part<64><<<2, 256, 0, stream>>>(g, NG, part);
    k_bn_adj<<<1, 64, 0, stream>>>(part, 2, NG, 64, lW, lb, 64, sc2, badj2);
    k_gemm_head<<<(NG + 31) / 32, 256, 0, stream>>>(g, lW, sc2, badj2, y, NG);

    k_bn_part<64><<<2, 256, 0, stream>>>(y, NG, part);
    k_bn_adj<<<1, 64, 0, stream>>>(part, 2, NG, 64, clW, clb, 10, sc3, badj3);
    k_cls<<<NG, 64, 0, stream>>>(y, clW, sc3, badj3, out);
}